// Round 1
// baseline (8990.018 us; speedup 1.0000x reference)
//
#include <hip/hip_runtime.h>
#include <stdint.h>
#include <math.h>

#define TSEQ   2048
#define NBATCH 2
#define NHEAD  16
#define HDIM   64
#define CDIM   1024

// ---------------------------------------------------------------------------
// threefry2x32, key (0,42), 20 rounds; returns y0 ^ y1 (JAX partitionable
// 32-bit random draw). Counter is (x0=hi32, x1=lo32) of the flat index.
// ---------------------------------------------------------------------------
__device__ __forceinline__ uint32_t rotl32(uint32_t x, int r) {
    return (x << r) | (x >> (32 - r));
}

__device__ __forceinline__ uint32_t tf2x32_xor(uint32_t x0, uint32_t x1) {
    const uint32_t ka = 0u, kb = 42u;
    const uint32_t kc = ka ^ kb ^ 0x1BD11BDAu;
    x0 += ka; x1 += kb;
#define TFR(r) { x0 += x1; x1 = rotl32(x1, r); x1 ^= x0; }
    TFR(13) TFR(15) TFR(26) TFR(6)
    x0 += kb; x1 += kc + 1u;
    TFR(17) TFR(29) TFR(16) TFR(24)
    x0 += kc; x1 += ka + 2u;
    TFR(13) TFR(15) TFR(26) TFR(6)
    x0 += ka; x1 += kb + 3u;
    TFR(17) TFR(29) TFR(16) TFR(24)
    x0 += kb; x1 += kc + 4u;
    TFR(13) TFR(15) TFR(26) TFR(6)
    x0 += kc; x1 += ka + 5u;
#undef TFR
    return x0 ^ x1;
}

// keep iff uniform(bits) < f32(0.9)  <=>  (bits>>9) < 7549747
#define KEEP_THRESH 7549747u

// ---------------------------------------------------------------------------
// Kernel 1: qkv = x @ w_attn + b_attn, scattered to Q/K/V in [B,H,T,D] f32
// M=4096 (B*T), K=1024, N=3072. 64x64 tile, BK=16, 256 thr, 4x4 per thread.
// ---------------------------------------------------------------------------
__global__ __launch_bounds__(256) void qkv_gemm(
    const float* __restrict__ x, const float* __restrict__ w,
    const float* __restrict__ bias,
    float* __restrict__ Q, float* __restrict__ K, float* __restrict__ V)
{
    __shared__ float As[16][64];  // As[k][m] (transposed)
    __shared__ float Bs[16][64];  // Bs[k][n]
    const int tid = threadIdx.x;
    const int bn = blockIdx.x, bm = blockIdx.y;
    const int tx = tid & 15, ty = tid >> 4;
    const int m0 = ty * 4, n0 = tx * 4;
    const int arow = tid >> 2, ac4 = (tid & 3) * 4;
    const int brow = tid >> 4, bc4 = (tid & 15) * 4;
    const float* xg = x + (size_t)(bm * 64 + arow) * 1024 + ac4;
    const float* wg = w + (size_t)brow * 3072 + bn * 64 + bc4;
    float acc[4][4] = {};
    for (int k0 = 0; k0 < 1024; k0 += 16) {
        float4 av = *(const float4*)(xg + k0);
        float4 bv = *(const float4*)(wg + (size_t)k0 * 3072);
        __syncthreads();
        As[ac4 + 0][arow] = av.x; As[ac4 + 1][arow] = av.y;
        As[ac4 + 2][arow] = av.z; As[ac4 + 3][arow] = av.w;
        *(float4*)&Bs[brow][bc4] = bv;
        __syncthreads();
#pragma unroll
        for (int kk = 0; kk < 16; ++kk) {
            float4 a = *(const float4*)&As[kk][m0];
            float4 b = *(const float4*)&Bs[kk][n0];
            const float aa[4] = {a.x, a.y, a.z, a.w};
            const float bb[4] = {b.x, b.y, b.z, b.w};
#pragma unroll
            for (int r = 0; r < 4; ++r)
#pragma unroll
                for (int c = 0; c < 4; ++c)
                    acc[r][c] = fmaf(aa[r], bb[c], acc[r][c]);
        }
    }
    const int gn = bn * 64 + n0;          // global col in [0,3072)
    const int which = gn >> 10;           // 0=q 1=k 2=v
    const int cc = gn & 1023;
    const int h = cc >> 6, d = cc & 63;
    float4 b4 = *(const float4*)(bias + gn);
    float* outp = which == 0 ? Q : (which == 1 ? K : V);
#pragma unroll
    for (int r = 0; r < 4; ++r) {
        const int grow = bm * 64 + m0 + r;         // 0..4095
        const int b = grow >> 11, t = grow & 2047; // batch, time
        float4 o;
        o.x = acc[r][0] + b4.x; o.y = acc[r][1] + b4.y;
        o.z = acc[r][2] + b4.z; o.w = acc[r][3] + b4.w;
        *(float4*)&outp[(((size_t)(b * NHEAD + h)) * TSEQ + t) * HDIM + d] = o;
    }
}

// ---------------------------------------------------------------------------
// Kernel 2: causal flash attention with exact JAX threefry dropout.
// Block = (qt, h, b): 64 q-rows, 256 threads, 4x4 per thread.
// Online softmax: l accumulates pre-dropout exp; dropout gates only the PV
// accumulation; final O = A / (l * 0.9).
// ---------------------------------------------------------------------------
__global__ __launch_bounds__(256) void attn_fwd(
    const float* __restrict__ Q, const float* __restrict__ K,
    const float* __restrict__ V, float* __restrict__ O)
{
    __shared__ float Qs[64][64];  // [d][m]
    __shared__ float Ks[64][64];  // [d][n]
    __shared__ float Vs[64][64];  // [n][d]
    __shared__ float Ps[64][64];  // [n][m]
    const int tid = threadIdx.x;
    const int qt = blockIdx.x, h = blockIdx.y, b = blockIdx.z;
    const int tx = tid & 15, ty = tid >> 4;
    const int m0 = ty * 4, n0 = tx * 4, d0 = tx * 4;
    const int q0 = qt * 64;
    const size_t headoff = ((size_t)(b * NHEAD + h)) * TSEQ * HDIM;
    const float* Qg = Q + headoff;
    const float* Kg = K + headoff;
    const float* Vg = V + headoff;

    // load Q tile (transposed into LDS)
#pragma unroll
    for (int i = 0; i < 4; ++i) {
        int f = i * 256 + tid;            // 0..1023 float4s
        int row = f >> 4, dc = (f & 15) * 4;
        float4 v4 = *(const float4*)(Qg + (size_t)(q0 + row) * HDIM + dc);
        Qs[dc + 0][row] = v4.x; Qs[dc + 1][row] = v4.y;
        Qs[dc + 2][row] = v4.z; Qs[dc + 3][row] = v4.w;
    }

    float A[4][4] = {};
    float mi[4] = {-INFINITY, -INFINITY, -INFINITY, -INFINITY};
    float li[4] = {0.f, 0.f, 0.f, 0.f};
    const uint32_t idxbase = (uint32_t)(b * NHEAD + h) * (uint32_t)TSEQ;

    for (int kt = 0; kt <= qt; ++kt) {
        __syncthreads();   // previous PV reads done before overwriting tiles
#pragma unroll
        for (int i = 0; i < 4; ++i) {
            int f = i * 256 + tid;
            int row = f >> 4, dc = (f & 15) * 4;
            float4 kv = *(const float4*)(Kg + (size_t)(kt * 64 + row) * HDIM + dc);
            Ks[dc + 0][row] = kv.x; Ks[dc + 1][row] = kv.y;
            Ks[dc + 2][row] = kv.z; Ks[dc + 3][row] = kv.w;
            float4 vv = *(const float4*)(Vg + (size_t)(kt * 64 + row) * HDIM + dc);
            *(float4*)&Vs[row][dc] = vv;
        }
        __syncthreads();

        // S = (Q K^T) tile
        float S[4][4] = {};
#pragma unroll
        for (int d = 0; d < 64; ++d) {
            float4 qa = *(const float4*)&Qs[d][m0];
            float4 kb = *(const float4*)&Ks[d][n0];
            const float aa[4] = {qa.x, qa.y, qa.z, qa.w};
            const float bb[4] = {kb.x, kb.y, kb.z, kb.w};
#pragma unroll
            for (int r = 0; r < 4; ++r)
#pragma unroll
                for (int c = 0; c < 4; ++c)
                    S[r][c] = fmaf(aa[r], bb[c], S[r][c]);
        }
        // scale + causal mask
#pragma unroll
        for (int r = 0; r < 4; ++r) {
            const int q = q0 + m0 + r;
#pragma unroll
            for (int c = 0; c < 4; ++c) {
                const int kk = kt * 64 + n0 + c;
                S[r][c] = (kk <= q) ? S[r][c] * 0.125f : -INFINITY;
            }
        }
        // online softmax (per row: 16-lane group reduce) + dropout + P to LDS
#pragma unroll
        for (int r = 0; r < 4; ++r) {
            const int q = q0 + m0 + r;
            float mx = fmaxf(fmaxf(S[r][0], S[r][1]), fmaxf(S[r][2], S[r][3]));
            mx = fmaxf(mx, __shfl_xor(mx, 1));
            mx = fmaxf(mx, __shfl_xor(mx, 2));
            mx = fmaxf(mx, __shfl_xor(mx, 4));
            mx = fmaxf(mx, __shfl_xor(mx, 8));
            const float mnew = fmaxf(mi[r], mx);
            const float alpha = expf(mi[r] - mnew);
            mi[r] = mnew;
            float e[4], rs = 0.f;
#pragma unroll
            for (int c = 0; c < 4; ++c) { e[c] = expf(S[r][c] - mnew); rs += e[c]; }
            rs += __shfl_xor(rs, 1); rs += __shfl_xor(rs, 2);
            rs += __shfl_xor(rs, 4); rs += __shfl_xor(rs, 8);
            li[r] = li[r] * alpha + rs;
#pragma unroll
            for (int c = 0; c < 4; ++c) A[r][c] *= alpha;
            const uint32_t rowbase = (idxbase + (uint32_t)q) * (uint32_t)TSEQ;
#pragma unroll
            for (int c = 0; c < 4; ++c) {
                const int kk = kt * 64 + n0 + c;
                float p = 0.f;
                if (kk <= q) {
                    const uint32_t bits = tf2x32_xor(0u, rowbase + (uint32_t)kk);
                    p = ((bits >> 9) < KEEP_THRESH) ? e[c] : 0.f;
                }
                Ps[n0 + c][m0 + r] = p;
            }
        }
        __syncthreads();
        // A[m][d] += sum_n P[n][m] * V[n][d]
#pragma unroll
        for (int n = 0; n < 64; ++n) {
            float4 pa = *(const float4*)&Ps[n][m0];
            float4 vb = *(const float4*)&Vs[n][d0];
            const float pp[4] = {pa.x, pa.y, pa.z, pa.w};
            const float vv[4] = {vb.x, vb.y, vb.z, vb.w};
#pragma unroll
            for (int r = 0; r < 4; ++r)
#pragma unroll
                for (int c = 0; c < 4; ++c)
                    A[r][c] = fmaf(pp[r], vv[c], A[r][c]);
        }
    }
    // write attn output in [B,T,C] layout
#pragma unroll
    for (int r = 0; r < 4; ++r) {
        const int q = q0 + m0 + r;
        const float inv = 1.0f / (li[r] * 0.9f);
        float4 o;
        o.x = A[r][0] * inv; o.y = A[r][1] * inv;
        o.z = A[r][2] * inv; o.w = A[r][3] * inv;
        *(float4*)&O[((size_t)(b * TSEQ + q)) * CDIM + h * HDIM + d0] = o;
    }
}

// ---------------------------------------------------------------------------
// Kernel 3: out = AO @ w_proj + b_proj   (M=4096, K=1024, N=1024)
// ---------------------------------------------------------------------------
__global__ __launch_bounds__(256) void proj_gemm(
    const float* __restrict__ xa, const float* __restrict__ w,
    const float* __restrict__ bias, float* __restrict__ out)
{
    __shared__ float As[16][64];
    __shared__ float Bs[16][64];
    const int tid = threadIdx.x;
    const int bn = blockIdx.x, bm = blockIdx.y;
    const int tx = tid & 15, ty = tid >> 4;
    const int m0 = ty * 4, n0 = tx * 4;
    const int arow = tid >> 2, ac4 = (tid & 3) * 4;
    const int brow = tid >> 4, bc4 = (tid & 15) * 4;
    const float* xg = xa + (size_t)(bm * 64 + arow) * 1024 + ac4;
    const float* wg = w + (size_t)brow * 1024 + bn * 64 + bc4;
    float acc[4][4] = {};
    for (int k0 = 0; k0 < 1024; k0 += 16) {
        float4 av = *(const float4*)(xg + k0);
        float4 bv = *(const float4*)(wg + (size_t)k0 * 1024);
        __syncthreads();
        As[ac4 + 0][arow] = av.x; As[ac4 + 1][arow] = av.y;
        As[ac4 + 2][arow] = av.z; As[ac4 + 3][arow] = av.w;
        *(float4*)&Bs[brow][bc4] = bv;
        __syncthreads();
#pragma unroll
        for (int kk = 0; kk < 16; ++kk) {
            float4 a = *(const float4*)&As[kk][m0];
            float4 b = *(const float4*)&Bs[kk][n0];
            const float aa[4] = {a.x, a.y, a.z, a.w};
            const float bb[4] = {b.x, b.y, b.z, b.w};
#pragma unroll
            for (int r = 0; r < 4; ++r)
#pragma unroll
                for (int c = 0; c < 4; ++c)
                    acc[r][c] = fmaf(aa[r], bb[c], acc[r][c]);
        }
    }
    const int gn = bn * 64 + n0;
    float4 b4 = *(const float4*)(bias + gn);
#pragma unroll
    for (int r = 0; r < 4; ++r) {
        const int grow = bm * 64 + m0 + r;
        float4 o;
        o.x = acc[r][0] + b4.x; o.y = acc[r][1] + b4.y;
        o.z = acc[r][2] + b4.z; o.w = acc[r][3] + b4.w;
        *(float4*)&out[(size_t)grow * 1024 + gn] = o;
    }
}

// ---------------------------------------------------------------------------
extern "C" void kernel_launch(void* const* d_in, const int* in_sizes, int n_in,
                              void* d_out, int out_size, void* d_ws, size_t ws_size,
                              hipStream_t stream)
{
    const float* x      = (const float*)d_in[0];
    const float* w_attn = (const float*)d_in[1];
    const float* b_attn = (const float*)d_in[2];
    const float* w_proj = (const float*)d_in[3];
    const float* b_proj = (const float*)d_in[4];
    float* out = (float*)d_out;

    float* ws = (float*)d_ws;
    const size_t n_head_elems = (size_t)NBATCH * NHEAD * TSEQ * HDIM; // 4,194,304
    float* Q  = ws;
    float* K  = Q + n_head_elems;
    float* V  = K + n_head_elems;
    float* AO = V + n_head_elems;   // attention output, [B,T,C]

    qkv_gemm<<<dim3(48, 64), 256, 0, stream>>>(x, w_attn, b_attn, Q, K, V);
    attn_fwd<<<dim3(TSEQ / 64, NHEAD, NBATCH), 256, 0, stream>>>(Q, K, V, AO);
    proj_gemm<<<dim3(16, 64), 256, 0, stream>>>(AO, w_proj, b_proj, out);
}

// Round 2
// 839.766 us; speedup vs baseline: 10.7054x; 10.7054x over previous
//
#include <hip/hip_runtime.h>
#include <hip/hip_bf16.h>
#include <stdint.h>
#include <math.h>

#define TSEQ   2048
#define NBATCH 2
#define NHEAD  16
#define HDIM   64
#define CDIM   1024

// keep iff uniform(bits) < f32(0.9)  <=>  (bits>>9) < 7549747
#define KEEP_THRESH 7549747u

typedef short  bf16x8 __attribute__((ext_vector_type(8)));
typedef float  f32x4  __attribute__((ext_vector_type(4)));

// ---------------------------------------------------------------------------
// threefry2x32, key (0,42), 20 rounds; returns y0 ^ y1 (JAX partitionable).
// ---------------------------------------------------------------------------
__device__ __forceinline__ uint32_t rotl32(uint32_t x, int r) {
    return (x << r) | (x >> (32 - r));
}

__device__ __forceinline__ uint32_t tf2x32_xor(uint32_t x0, uint32_t x1) {
    const uint32_t ka = 0u, kb = 42u;
    const uint32_t kc = ka ^ kb ^ 0x1BD11BDAu;
    x0 += ka; x1 += kb;
#define TFR(r) { x0 += x1; x1 = rotl32(x1, r); x1 ^= x0; }
    TFR(13) TFR(15) TFR(26) TFR(6)
    x0 += kb; x1 += kc + 1u;
    TFR(17) TFR(29) TFR(16) TFR(24)
    x0 += kc; x1 += ka + 2u;
    TFR(13) TFR(15) TFR(26) TFR(6)
    x0 += ka; x1 += kb + 3u;
    TFR(17) TFR(29) TFR(16) TFR(24)
    x0 += kb; x1 += kc + 4u;
    TFR(13) TFR(15) TFR(26) TFR(6)
    x0 += kc; x1 += ka + 5u;
#undef TFR
    return x0 ^ x1;
}

__device__ __forceinline__ bool tf_keep(uint32_t idx) {
    return (tf2x32_xor(0u, idx) >> 9) < KEEP_THRESH;
}

__device__ __forceinline__ ushort f2bf(float f) {
    __hip_bfloat16 h = __float2bfloat16(f);
    return *reinterpret_cast<ushort*>(&h);
}

__device__ __forceinline__ void async_copy16(void* lds, const void* g) {
    __builtin_amdgcn_global_load_lds(
        (const __attribute__((address_space(1))) unsigned int*)g,
        (__attribute__((address_space(3))) unsigned int*)lds, 16, 0, 0);
}

// ---------------------------------------------------------------------------
// Kernel 1: qkv = x @ w_attn + b_attn -> bf16 Q/K/V in [B,H,T,D]
// M=4096, K=1024, N=3072. 64x64 tile, BK=16, 256 thr, 4x4 per thread. f32 math.
// ---------------------------------------------------------------------------
__global__ __launch_bounds__(256) void qkv_gemm(
    const float* __restrict__ x, const float* __restrict__ w,
    const float* __restrict__ bias,
    ushort* __restrict__ Qb, ushort* __restrict__ Kb, ushort* __restrict__ Vb)
{
    __shared__ float As[16][64];  // As[k][m]
    __shared__ float Bs[16][64];  // Bs[k][n]
    const int tid = threadIdx.x;
    const int bn = blockIdx.x, bm = blockIdx.y;
    const int tx = tid & 15, ty = tid >> 4;
    const int m0 = ty * 4, n0 = tx * 4;
    const int arow = tid >> 2, ac4 = (tid & 3) * 4;
    const int brow = tid >> 4, bc4 = (tid & 15) * 4;
    const float* xg = x + (size_t)(bm * 64 + arow) * 1024 + ac4;
    const float* wg = w + (size_t)brow * 3072 + bn * 64 + bc4;
    float acc[4][4] = {};
    for (int k0 = 0; k0 < 1024; k0 += 16) {
        float4 av = *(const float4*)(xg + k0);
        float4 bv = *(const float4*)(wg + (size_t)k0 * 3072);
        __syncthreads();
        As[ac4 + 0][arow] = av.x; As[ac4 + 1][arow] = av.y;
        As[ac4 + 2][arow] = av.z; As[ac4 + 3][arow] = av.w;
        *(float4*)&Bs[brow][bc4] = bv;
        __syncthreads();
#pragma unroll
        for (int kk = 0; kk < 16; ++kk) {
            float4 a = *(const float4*)&As[kk][m0];
            float4 b = *(const float4*)&Bs[kk][n0];
            const float aa[4] = {a.x, a.y, a.z, a.w};
            const float bb[4] = {b.x, b.y, b.z, b.w};
#pragma unroll
            for (int r = 0; r < 4; ++r)
#pragma unroll
                for (int c = 0; c < 4; ++c)
                    acc[r][c] = fmaf(aa[r], bb[c], acc[r][c]);
        }
    }
    const int gn = bn * 64 + n0;          // global col in [0,3072)
    const int which = gn >> 10;           // 0=q 1=k 2=v
    const int cc = gn & 1023;
    const int h = cc >> 6, d = cc & 63;
    float4 b4 = *(const float4*)(bias + gn);
    ushort* outp = which == 0 ? Qb : (which == 1 ? Kb : Vb);
#pragma unroll
    for (int r = 0; r < 4; ++r) {
        const int grow = bm * 64 + m0 + r;
        const int b = grow >> 11, t = grow & 2047;
        ushort4 o4;
        o4.x = f2bf(acc[r][0] + b4.x);
        o4.y = f2bf(acc[r][1] + b4.y);
        o4.z = f2bf(acc[r][2] + b4.z);
        o4.w = f2bf(acc[r][3] + b4.w);
        *(ushort4*)&outp[(((size_t)(b * NHEAD + h)) * TSEQ + t) * HDIM + d] = o4;
    }
}

// ---------------------------------------------------------------------------
// Kernel 2: causal flash attention, bf16 MFMA, exact threefry dropout.
// Block: 256 thr = 4 waves; 64 q-rows/block (16/wave); KVBLK=64.
// LDS (all XOR-swizzled, ushort idx = row*64 + (col ^ ((row&7)<<3))):
//   Ks[k][d]  (K tile, staged via swizzled-source global_load_lds)
//   Vt[d][k]  (V transposed, reg-staged with staggered b16 writes)
//   Ps[q][k]  (P post-softmax post-dropout, per-wave private rows)
// MFMA 16x16x32 bf16: A row=l&15 k=(l>>4)*8+i; B col=l&15 same k;
//                     D col=l&15 row=(l>>4)*4+r.
// ---------------------------------------------------------------------------
__global__ __launch_bounds__(256) void attn_fwd_mfma(
    const ushort* __restrict__ Qb, const ushort* __restrict__ Kb,
    const ushort* __restrict__ Vb, float* __restrict__ AO)
{
    __shared__ ushort Ks[64 * 64];
    __shared__ ushort Vt[64 * 64];
    __shared__ ushort Ps[64 * 64];
    const int tid = threadIdx.x;
    const int lane = tid & 63;
    const int wid = tid >> 6;
    const int l15 = lane & 15, l4 = lane >> 4;
    const int qt = (int)gridDim.x - 1 - (int)blockIdx.x;  // heavy blocks first
    const int h = blockIdx.y, b = blockIdx.z;
    const int q0 = qt * 64;
    const int hb = b * NHEAD + h;
    const size_t headoff = (size_t)hb * TSEQ * HDIM;
    const ushort* Qg = Qb + headoff;
    const ushort* Kg = Kb + headoff;
    const ushort* Vg = Vb + headoff;

    // Q fragments in registers (wave strip = rows q0+wid*16 .. +15)
    bf16x8 qf0, qf1;
    {
        const ushort* qrow = Qg + (size_t)(q0 + wid * 16 + l15) * HDIM;
        qf0 = *(const bf16x8*)(qrow + l4 * 8);
        qf1 = *(const bf16x8*)(qrow + 32 + l4 * 8);
    }

    f32x4 oacc[4];
#pragma unroll
    for (int i = 0; i < 4; ++i) oacc[i] = (f32x4){0.f, 0.f, 0.f, 0.f};
    float mi[4] = {-INFINITY, -INFINITY, -INFINITY, -INFINITY};
    float li[4] = {0.f, 0.f, 0.f, 0.f};

    for (int kt = 0; kt <= qt; ++kt) {
        __syncthreads();  // previous tile fully consumed
        // ---- stage K (async, swizzled global source -> linear LDS dest)
        {
            const ushort* Kt = Kg + (size_t)(kt * 64) * HDIM;
#pragma unroll
            for (int c = 0; c < 2; ++c) {
                const int rbase = wid * 16 + c * 8;       // wave-uniform
                const int row = rbase + (lane >> 3);
                const ushort* src = Kt + row * 64 + (((lane & 7) * 8) ^ ((row & 7) << 3));
                async_copy16(&Ks[rbase * 64], src);
            }
        }
        // ---- stage V transposed (reg path, staggered b16 writes)
        {
            const ushort* Vtg = Vg + (size_t)(kt * 64) * HDIM;
#pragma unroll
            for (int rnd = 0; rnd < 2; ++rnd) {
                const int flat = rnd * 256 + tid;      // 0..511
                const int kk = flat >> 3;              // 0..63
                const int d0v = (flat & 7) * 8;
                union { uint4 u; ushort s[8]; } u;
                u.u = *(const uint4*)(Vtg + kk * 64 + d0v);
#pragma unroll
                for (int jj = 0; jj < 8; ++jj) {
                    const int e = (jj + (tid & 7)) & 7;   // stagger: d&7 varies/lane
                    const int d = d0v + e;
                    Vt[d * 64 + (kk ^ (e << 3))] = u.s[e];
                }
            }
        }
        __syncthreads();

        // ---- S = Q K^T (4 col-tiles of 16, K-dim = d = 64 -> 2 MFMA each)
        f32x4 s4[4];
#pragma unroll
        for (int ct = 0; ct < 4; ++ct) {
            const int krow = ct * 16 + l15;
            const int sw = (krow & 7) << 3;
            bf16x8 kf0 = *(const bf16x8*)&Ks[krow * 64 + ((l4 * 8) ^ sw)];
            bf16x8 kf1 = *(const bf16x8*)&Ks[krow * 64 + ((l4 * 8 + 32) ^ sw)];
            f32x4 a = {0.f, 0.f, 0.f, 0.f};
            a = __builtin_amdgcn_mfma_f32_16x16x32_bf16(qf0, kf0, a, 0, 0, 0);
            a = __builtin_amdgcn_mfma_f32_16x16x32_bf16(qf1, kf1, a, 0, 0, 0);
            s4[ct] = a;
        }

        // ---- online softmax (f32, D-layout rows), li pre-dropout
        float ev[4][4];
        float alpha[4];
#pragma unroll
        for (int r = 0; r < 4; ++r) {
            const int qglob = q0 + wid * 16 + l4 * 4 + r;
            float sv[4];
#pragma unroll
            for (int ct = 0; ct < 4; ++ct) {
                const int kglob = kt * 64 + ct * 16 + l15;
                const float xx = s4[ct][r] * 0.125f;
                sv[ct] = (kglob <= qglob) ? xx : -INFINITY;
            }
            float mx = fmaxf(fmaxf(sv[0], sv[1]), fmaxf(sv[2], sv[3]));
            mx = fmaxf(mx, __shfl_xor(mx, 1));
            mx = fmaxf(mx, __shfl_xor(mx, 2));
            mx = fmaxf(mx, __shfl_xor(mx, 4));
            mx = fmaxf(mx, __shfl_xor(mx, 8));
            const float mnew = fmaxf(mi[r], mx);
            alpha[r] = __expf(mi[r] - mnew);
            mi[r] = mnew;
            float rs = 0.f;
#pragma unroll
            for (int ct = 0; ct < 4; ++ct) { ev[r][ct] = __expf(sv[ct] - mnew); rs += ev[r][ct]; }
            rs += __shfl_xor(rs, 1); rs += __shfl_xor(rs, 2);
            rs += __shfl_xor(rs, 4); rs += __shfl_xor(rs, 8);
            li[r] = li[r] * alpha[r] + rs;
        }
#pragma unroll
        for (int dt = 0; dt < 4; ++dt)
#pragma unroll
            for (int r = 0; r < 4; ++r) oacc[dt][r] *= alpha[r];

        // ---- exact threefry dropout gate + P -> LDS (bf16, own rows only)
#pragma unroll
        for (int r = 0; r < 4; ++r) {
            const int qglob = q0 + wid * 16 + l4 * 4 + r;
            const uint32_t rowbase = ((uint32_t)hb * TSEQ + (uint32_t)qglob) * TSEQ;
            const int qrow = wid * 16 + l4 * 4 + r;
            const int swp = (qrow & 7) << 3;
            ushort* pr = &Ps[qrow * 64];
#pragma unroll
            for (int ct = 0; ct < 4; ++ct) {
                const int kloc = ct * 16 + l15;
                const int kglob = kt * 64 + kloc;
                const float p = tf_keep(rowbase + (uint32_t)kglob) ? ev[r][ct] : 0.f;
                pr[kloc ^ swp] = f2bf(p);
            }
        }

        // ---- O += P V  (A=P from own Ps rows, B=V from Vt; 4 d-tiles x 2 k-halves)
        const int prow = wid * 16 + l15;
        const int swq = (l15 & 7) << 3;
        bf16x8 pa0 = *(const bf16x8*)&Ps[prow * 64 + ((l4 * 8) ^ swq)];
        bf16x8 pa1 = *(const bf16x8*)&Ps[prow * 64 + ((l4 * 8 + 32) ^ swq)];
#pragma unroll
        for (int dt = 0; dt < 4; ++dt) {
            const int drow = dt * 16 + l15;
            const int swv = (drow & 7) << 3;
            bf16x8 vf0 = *(const bf16x8*)&Vt[drow * 64 + ((l4 * 8) ^ swv)];
            bf16x8 vf1 = *(const bf16x8*)&Vt[drow * 64 + ((l4 * 8 + 32) ^ swv)];
            oacc[dt] = __builtin_amdgcn_mfma_f32_16x16x32_bf16(pa0, vf0, oacc[dt], 0, 0, 0);
            oacc[dt] = __builtin_amdgcn_mfma_f32_16x16x32_bf16(pa1, vf1, oacc[dt], 0, 0, 0);
        }
    }

    // ---- epilogue: O = acc / (li * 0.9), write f32 [B,T,C]
#pragma unroll
    for (int r = 0; r < 4; ++r) {
        const int qglob = q0 + wid * 16 + l4 * 4 + r;
        const float inv = 1.0f / (li[r] * 0.9f);
        float* orow = AO + ((size_t)(b * TSEQ + qglob)) * CDIM + h * HDIM;
#pragma unroll
        for (int dt = 0; dt < 4; ++dt)
            orow[dt * 16 + l15] = oacc[dt][r] * inv;
    }
}

// ---------------------------------------------------------------------------
// Kernel 3: out = AO @ w_proj + b_proj   (M=4096, K=1024, N=1024) f32
// ---------------------------------------------------------------------------
__global__ __launch_bounds__(256) void proj_gemm(
    const float* __restrict__ xa, const float* __restrict__ w,
    const float* __restrict__ bias, float* __restrict__ out)
{
    __shared__ float As[16][64];
    __shared__ float Bs[16][64];
    const int tid = threadIdx.x;
    const int bn = blockIdx.x, bm = blockIdx.y;
    const int tx = tid & 15, ty = tid >> 4;
    const int m0 = ty * 4, n0 = tx * 4;
    const int arow = tid >> 2, ac4 = (tid & 3) * 4;
    const int brow = tid >> 4, bc4 = (tid & 15) * 4;
    const float* xg = xa + (size_t)(bm * 64 + arow) * 1024 + ac4;
    const float* wg = w + (size_t)brow * 1024 + bn * 64 + bc4;
    float acc[4][4] = {};
    for (int k0 = 0; k0 < 1024; k0 += 16) {
        float4 av = *(const float4*)(xg + k0);
        float4 bv = *(const float4*)(wg + (size_t)k0 * 1024);
        __syncthreads();
        As[ac4 + 0][arow] = av.x; As[ac4 + 1][arow] = av.y;
        As[ac4 + 2][arow] = av.z; As[ac4 + 3][arow] = av.w;
        *(float4*)&Bs[brow][bc4] = bv;
        __syncthreads();
#pragma unroll
        for (int kk = 0; kk < 16; ++kk) {
            float4 a = *(const float4*)&As[kk][m0];
            float4 b = *(const float4*)&Bs[kk][n0];
            const float aa[4] = {a.x, a.y, a.z, a.w};
            const float bb[4] = {b.x, b.y, b.z, b.w};
#pragma unroll
            for (int r = 0; r < 4; ++r)
#pragma unroll
                for (int c = 0; c < 4; ++c)
                    acc[r][c] = fmaf(aa[r], bb[c], acc[r][c]);
        }
    }
    const int gn = bn * 64 + n0;
    float4 b4 = *(const float4*)(bias + gn);
#pragma unroll
    for (int r = 0; r < 4; ++r) {
        const int grow = bm * 64 + m0 + r;
        float4 o;
        o.x = acc[r][0] + b4.x; o.y = acc[r][1] + b4.y;
        o.z = acc[r][2] + b4.z; o.w = acc[r][3] + b4.w;
        *(float4*)&out[(size_t)grow * 1024 + gn] = o;
    }
}

// ---------------------------------------------------------------------------
extern "C" void kernel_launch(void* const* d_in, const int* in_sizes, int n_in,
                              void* d_out, int out_size, void* d_ws, size_t ws_size,
                              hipStream_t stream)
{
    const float* x      = (const float*)d_in[0];
    const float* w_attn = (const float*)d_in[1];
    const float* b_attn = (const float*)d_in[2];
    const float* w_proj = (const float*)d_in[3];
    const float* b_proj = (const float*)d_in[4];
    float* out = (float*)d_out;

    const size_t NH = (size_t)NBATCH * NHEAD * TSEQ * HDIM;  // 4,194,304
    ushort* Qb = (ushort*)d_ws;
    ushort* Kb = Qb + NH;
    ushort* Vb = Kb + NH;
    float*  AO = (float*)(Vb + NH);

    qkv_gemm<<<dim3(48, 64), 256, 0, stream>>>(x, w_attn, b_attn, Qb, Kb, Vb);
    attn_fwd_mfma<<<dim3(TSEQ / 64, NHEAD, NBATCH), 256, 0, stream>>>(Qb, Kb, Vb, AO);
    proj_gemm<<<dim3(16, 64), 256, 0, stream>>>(AO, w_proj, b_proj, out);
}

// Round 3
// 432.142 us; speedup vs baseline: 20.8034x; 1.9433x over previous
//
#include <hip/hip_runtime.h>
#include <hip/hip_bf16.h>
#include <stdint.h>
#include <math.h>

#define TSEQ   2048
#define NBATCH 2
#define NHEAD  16
#define HDIM   64
#define CDIM   1024

// keep iff uniform(bits) < f32(0.9)  <=>  (bits>>9) < 7549747
#define KEEP_THRESH 7549747u

typedef short  bf16x8 __attribute__((ext_vector_type(8)));
typedef float  f32x4  __attribute__((ext_vector_type(4)));

// ---------------------------------------------------------------------------
// threefry2x32, key (0,42), 20 rounds; returns y0 ^ y1 (JAX partitionable).
// ---------------------------------------------------------------------------
__device__ __forceinline__ uint32_t rotl32(uint32_t x, int r) {
    return (x << r) | (x >> (32 - r));
}

__device__ __forceinline__ uint32_t tf2x32_xor(uint32_t x0, uint32_t x1) {
    const uint32_t ka = 0u, kb = 42u;
    const uint32_t kc = ka ^ kb ^ 0x1BD11BDAu;
    x0 += ka; x1 += kb;
#define TFR(r) { x0 += x1; x1 = rotl32(x1, r); x1 ^= x0; }
    TFR(13) TFR(15) TFR(26) TFR(6)
    x0 += kb; x1 += kc + 1u;
    TFR(17) TFR(29) TFR(16) TFR(24)
    x0 += kc; x1 += ka + 2u;
    TFR(13) TFR(15) TFR(26) TFR(6)
    x0 += ka; x1 += kb + 3u;
    TFR(17) TFR(29) TFR(16) TFR(24)
    x0 += kb; x1 += kc + 4u;
    TFR(13) TFR(15) TFR(26) TFR(6)
    x0 += kc; x1 += ka + 5u;
#undef TFR
    return x0 ^ x1;
}

__device__ __forceinline__ bool tf_keep(uint32_t idx) {
    return (tf2x32_xor(0u, idx) >> 9) < KEEP_THRESH;
}

__device__ __forceinline__ ushort f2bf(float f) {
    __hip_bfloat16 h = __float2bfloat16(f);
    return *reinterpret_cast<ushort*>(&h);
}

__device__ __forceinline__ void async_copy16(void* lds, const void* g) {
    __builtin_amdgcn_global_load_lds(
        (const __attribute__((address_space(1))) unsigned int*)g,
        (__attribute__((address_space(3))) unsigned int*)lds, 16, 0, 0);
}

// ---------------------------------------------------------------------------
// x f32 -> bf16 (same layout), 8 elems/thread
// ---------------------------------------------------------------------------
__global__ __launch_bounds__(256) void cvt_bf16(
    const float* __restrict__ src, ushort* __restrict__ dst, int n)
{
    int idx = (blockIdx.x * 256 + threadIdx.x) * 8;
    if (idx >= n) return;
    float4 a = *(const float4*)(src + idx);
    float4 b = *(const float4*)(src + idx + 4);
    ushort4 o1; o1.x = f2bf(a.x); o1.y = f2bf(a.y); o1.z = f2bf(a.z); o1.w = f2bf(a.w);
    ushort4 o2; o2.x = f2bf(b.x); o2.y = f2bf(b.y); o2.z = f2bf(b.z); o2.w = f2bf(b.w);
    *(ushort4*)(dst + idx) = o1;
    *(ushort4*)(dst + idx + 4) = o2;
}

// ---------------------------------------------------------------------------
// w f32 [K][N] -> bf16 [N][K]  (32x32 LDS tiles)
// ---------------------------------------------------------------------------
__global__ __launch_bounds__(256) void transpose_cvt(
    const float* __restrict__ src, ushort* __restrict__ dst, int K, int N)
{
    __shared__ float t[32][33];
    const int n0 = blockIdx.x * 32, k0 = blockIdx.y * 32;
    const int i = threadIdx.x;
    {
        int k = i >> 3, n4 = (i & 7) * 4;
        float4 v = *(const float4*)(src + (size_t)(k0 + k) * N + n0 + n4);
        t[k][n4 + 0] = v.x; t[k][n4 + 1] = v.y; t[k][n4 + 2] = v.z; t[k][n4 + 3] = v.w;
    }
    __syncthreads();
    {
        int n = i >> 3, k4 = (i & 7) * 4;
        ushort4 o;
        o.x = f2bf(t[k4 + 0][n]); o.y = f2bf(t[k4 + 1][n]);
        o.z = f2bf(t[k4 + 2][n]); o.w = f2bf(t[k4 + 3][n]);
        *(ushort4*)(dst + (size_t)(n0 + n) * K + k0 + k4) = o;
    }
}

// ---------------------------------------------------------------------------
// bf16 MFMA GEMM: C[M][N] = A[M][K] * Bt[N][K]^T + bias
// 128x128 tile, BK=32, 256 thr = 4 waves (2x2), double-buffered LDS,
// global_load_lds width-16 staging, conflict-free [row][32] fragment reads.
// MODE 0: C = f32 out.  MODE 1: scatter bf16 into Q/K/V [B,H,T,D].
// ---------------------------------------------------------------------------
template<int MODE>
__global__ __launch_bounds__(256) void gemm_bf16(
    const ushort* __restrict__ A, const ushort* __restrict__ Bt,
    const float* __restrict__ bias,
    ushort* __restrict__ Q, ushort* __restrict__ Kq, ushort* __restrict__ V,
    float* __restrict__ Cf, int M, int N, int K)
{
    __shared__ ushort As[2][128 * 32];
    __shared__ ushort Bs[2][128 * 32];
    const int tid = threadIdx.x, lane = tid & 63, wid = tid >> 6;
    const int l15 = lane & 15, l4 = lane >> 4;
    const int wr = wid >> 1, wc = wid & 1;
    const int bn = blockIdx.x, bm = blockIdx.y;
    const int NTK = K >> 5;

    f32x4 acc[4][4];
#pragma unroll
    for (int m = 0; m < 4; ++m)
#pragma unroll
        for (int n = 0; n < 4; ++n) acc[m][n] = (f32x4){0.f, 0.f, 0.f, 0.f};

    auto stage = [&](int p, int k0) {
#pragma unroll
        for (int j = 0; j < 2; ++j) {
            const int rbase = wid * 32 + j * 16;
            const int row = rbase + (lane >> 2);
            const ushort* src = A + (size_t)(bm * 128 + row) * K + k0 + (lane & 3) * 8;
            async_copy16(&As[p][rbase * 32], src);
        }
#pragma unroll
        for (int j = 0; j < 2; ++j) {
            const int rbase = wid * 32 + j * 16;
            const int row = rbase + (lane >> 2);
            const ushort* src = Bt + (size_t)(bn * 128 + row) * K + k0 + (lane & 3) * 8;
            async_copy16(&Bs[p][rbase * 32], src);
        }
    };
    auto compute = [&](int p) {
        bf16x8 af[4], bf[4];
#pragma unroll
        for (int m = 0; m < 4; ++m)
            af[m] = *(const bf16x8*)&As[p][(wr * 64 + m * 16 + l15) * 32 + l4 * 8];
#pragma unroll
        for (int n = 0; n < 4; ++n)
            bf[n] = *(const bf16x8*)&Bs[p][(wc * 64 + n * 16 + l15) * 32 + l4 * 8];
#pragma unroll
        for (int m = 0; m < 4; ++m)
#pragma unroll
            for (int n = 0; n < 4; ++n)
                acc[m][n] = __builtin_amdgcn_mfma_f32_16x16x32_bf16(af[m], bf[n], acc[m][n], 0, 0, 0);
    };

    stage(0, 0);
    __syncthreads();
    for (int t = 0; t < NTK; ++t) {
        const int p = t & 1;
        if (t + 1 < NTK) stage(p ^ 1, (t + 1) << 5);
        compute(p);
        __syncthreads();
    }

    const int colbase = bn * 128 + wc * 64;
    const int rowbase = bm * 128 + wr * 64;
    if (MODE == 0) {
#pragma unroll
        for (int n = 0; n < 4; ++n) {
            const int col = colbase + n * 16 + l15;
            const float bv = bias[col];
#pragma unroll
            for (int m = 0; m < 4; ++m)
#pragma unroll
                for (int r = 0; r < 4; ++r) {
                    const int row = rowbase + m * 16 + l4 * 4 + r;
                    Cf[(size_t)row * N + col] = acc[m][n][r] + bv;
                }
        }
    } else {
#pragma unroll
        for (int n = 0; n < 4; ++n) {
            const int col = colbase + n * 16 + l15;
            const int which = col >> 10, cc = col & 1023;
            const int hh = cc >> 6, dd = cc & 63;
            ushort* outp = which == 0 ? Q : (which == 1 ? Kq : V);
            const float bv = bias[col];
#pragma unroll
            for (int m = 0; m < 4; ++m)
#pragma unroll
                for (int r = 0; r < 4; ++r) {
                    const int row = rowbase + m * 16 + l4 * 4 + r;
                    const int bb = row >> 11, tt = row & 2047;
                    outp[(((size_t)(bb * NHEAD + hh)) * TSEQ + tt) * HDIM + dd] =
                        f2bf(acc[m][n][r] + bv);
                }
        }
    }
}

// ---------------------------------------------------------------------------
// Kernel 2: causal flash attention, bf16 MFMA, exact threefry dropout.
// 256 thr = 4 waves, 64 q-rows/block (16/wave), KVBLK=64.
// Double-buffered K (async glds, swizzled source) and V (reg-staged,
// issue-early / write-late). ONE barrier per k-tile.
// ---------------------------------------------------------------------------
__global__ __launch_bounds__(256) void attn_fwd_mfma(
    const ushort* __restrict__ Qb, const ushort* __restrict__ Kb,
    const ushort* __restrict__ Vb, ushort* __restrict__ AO)
{
    __shared__ ushort Ks[2][64 * 64];
    __shared__ ushort Vt[2][64 * 64];
    __shared__ ushort Ps[64 * 64];
    const int tid = threadIdx.x;
    const int lane = tid & 63;
    const int wid = tid >> 6;
    const int l15 = lane & 15, l4 = lane >> 4;
    const int qt = (int)gridDim.x - 1 - (int)blockIdx.x;  // heavy blocks first
    const int h = blockIdx.y, b = blockIdx.z;
    const int q0 = qt * 64;
    const int hb = b * NHEAD + h;
    const size_t headoff = (size_t)hb * TSEQ * HDIM;
    const ushort* Qg = Qb + headoff;
    const ushort* Kg = Kb + headoff;
    const ushort* Vg = Vb + headoff;

    // Q fragments in registers
    bf16x8 qf0, qf1;
    {
        const ushort* qrow = Qg + (size_t)(q0 + wid * 16 + l15) * HDIM;
        qf0 = *(const bf16x8*)(qrow + l4 * 8);
        qf1 = *(const bf16x8*)(qrow + 32 + l4 * 8);
    }

    f32x4 oacc[4];
#pragma unroll
    for (int i = 0; i < 4; ++i) oacc[i] = (f32x4){0.f, 0.f, 0.f, 0.f};
    float mi[4] = {-INFINITY, -INFINITY, -INFINITY, -INFINITY};
    float li[4] = {0.f, 0.f, 0.f, 0.f};

    auto stageK = [&](int p, int kt) {
        const ushort* Kt = Kg + (size_t)(kt * 64) * HDIM;
#pragma unroll
        for (int c = 0; c < 2; ++c) {
            const int rbase = wid * 16 + c * 8;     // wave-uniform
            const int row = rbase + (lane >> 3);
            const ushort* src = Kt + row * 64 + (((lane & 7) * 8) ^ ((row & 7) << 3));
            async_copy16(&Ks[p][rbase * 64], src);
        }
    };
    uint4 vreg[2];
    auto loadV = [&](int kt) {
        const ushort* Vtg = Vg + (size_t)(kt * 64) * HDIM;
#pragma unroll
        for (int rnd = 0; rnd < 2; ++rnd) {
            const int flat = rnd * 256 + tid;
            const int kk = flat >> 3, d0v = (flat & 7) * 8;
            vreg[rnd] = *(const uint4*)(Vtg + kk * 64 + d0v);
        }
    };
    auto writeV = [&](int p) {
#pragma unroll
        for (int rnd = 0; rnd < 2; ++rnd) {
            const int flat = rnd * 256 + tid;
            const int kk = flat >> 3, d0v = (flat & 7) * 8;
            union { uint4 u; ushort s[8]; } u;
            u.u = vreg[rnd];
#pragma unroll
            for (int jj = 0; jj < 8; ++jj) {
                const int e = (jj + (tid & 7)) & 7;   // stagger across lanes
                const int d = d0v + e;
                Vt[p][d * 64 + (kk ^ ((d & 7) << 3))] = u.s[e];
            }
        }
    };

    // prologue: tile 0
    stageK(0, 0);
    loadV(0);
    writeV(0);        // compiler waits vreg; glds drained by syncthreads below
    __syncthreads();

    for (int kt = 0; kt <= qt; ++kt) {
        const int p = kt & 1;
        const bool pf = (kt < qt);
        if (pf) { stageK(p ^ 1, kt + 1); loadV(kt + 1); }

        // ---- S = Q K^T from Ks[p]
        f32x4 s4[4];
#pragma unroll
        for (int ct = 0; ct < 4; ++ct) {
            const int krow = ct * 16 + l15;
            const int sw = (krow & 7) << 3;
            bf16x8 kf0 = *(const bf16x8*)&Ks[p][krow * 64 + ((l4 * 8) ^ sw)];
            bf16x8 kf1 = *(const bf16x8*)&Ks[p][krow * 64 + ((l4 * 8 + 32) ^ sw)];
            f32x4 a = {0.f, 0.f, 0.f, 0.f};
            a = __builtin_amdgcn_mfma_f32_16x16x32_bf16(qf0, kf0, a, 0, 0, 0);
            a = __builtin_amdgcn_mfma_f32_16x16x32_bf16(qf1, kf1, a, 0, 0, 0);
            s4[ct] = a;
        }

        // ---- online softmax (li pre-dropout)
        float ev[4][4];
        float alpha[4];
#pragma unroll
        for (int r = 0; r < 4; ++r) {
            const int qglob = q0 + wid * 16 + l4 * 4 + r;
            float sv[4];
#pragma unroll
            for (int ct = 0; ct < 4; ++ct) {
                const int kglob = kt * 64 + ct * 16 + l15;
                const float xx = s4[ct][r] * 0.125f;
                sv[ct] = (kglob <= qglob) ? xx : -INFINITY;
            }
            float mx = fmaxf(fmaxf(sv[0], sv[1]), fmaxf(sv[2], sv[3]));
            mx = fmaxf(mx, __shfl_xor(mx, 1));
            mx = fmaxf(mx, __shfl_xor(mx, 2));
            mx = fmaxf(mx, __shfl_xor(mx, 4));
            mx = fmaxf(mx, __shfl_xor(mx, 8));
            const float mnew = fmaxf(mi[r], mx);
            alpha[r] = __expf(mi[r] - mnew);
            mi[r] = mnew;
            float rs = 0.f;
#pragma unroll
            for (int ct = 0; ct < 4; ++ct) { ev[r][ct] = __expf(sv[ct] - mnew); rs += ev[r][ct]; }
            rs += __shfl_xor(rs, 1); rs += __shfl_xor(rs, 2);
            rs += __shfl_xor(rs, 4); rs += __shfl_xor(rs, 8);
            li[r] = li[r] * alpha[r] + rs;
        }
#pragma unroll
        for (int dt = 0; dt < 4; ++dt)
#pragma unroll
            for (int r = 0; r < 4; ++r) oacc[dt][r] *= alpha[r];

        // ---- exact threefry dropout + P -> LDS (bf16, own rows only)
#pragma unroll
        for (int r = 0; r < 4; ++r) {
            const int qglob = q0 + wid * 16 + l4 * 4 + r;
            const uint32_t rowbase = ((uint32_t)hb * TSEQ + (uint32_t)qglob) * TSEQ;
            const int qrow = wid * 16 + l4 * 4 + r;
            const int swp = (qrow & 7) << 3;
            ushort* pr = &Ps[qrow * 64];
#pragma unroll
            for (int ct = 0; ct < 4; ++ct) {
                const int kloc = ct * 16 + l15;
                const int kglob = kt * 64 + kloc;
                const float pv = tf_keep(rowbase + (uint32_t)kglob) ? ev[r][ct] : 0.f;
                pr[kloc ^ swp] = f2bf(pv);
            }
        }

        // ---- O += P V from Vt[p]
        const int prow = wid * 16 + l15;
        const int swq = (l15 & 7) << 3;
        bf16x8 pa0 = *(const bf16x8*)&Ps[prow * 64 + ((l4 * 8) ^ swq)];
        bf16x8 pa1 = *(const bf16x8*)&Ps[prow * 64 + ((l4 * 8 + 32) ^ swq)];
#pragma unroll
        for (int dt = 0; dt < 4; ++dt) {
            const int drow = dt * 16 + l15;
            const int swv = (drow & 7) << 3;
            bf16x8 vf0 = *(const bf16x8*)&Vt[p][drow * 64 + ((l4 * 8) ^ swv)];
            bf16x8 vf1 = *(const bf16x8*)&Vt[p][drow * 64 + ((l4 * 8 + 32) ^ swv)];
            oacc[dt] = __builtin_amdgcn_mfma_f32_16x16x32_bf16(pa0, vf0, oacc[dt], 0, 0, 0);
            oacc[dt] = __builtin_amdgcn_mfma_f32_16x16x32_bf16(pa1, vf1, oacc[dt], 0, 0, 0);
        }

        // write-late: V(kt+1) into the other buffer (safe: vb[p^1] readers
        // finished before the barrier that ended iter kt-1)
        if (pf) writeV(p ^ 1);
        __syncthreads();   // drains glds (vmcnt0) + orders V writes for all
    }

    // ---- epilogue: AO (bf16, [B,T,C]) = acc / (li * 0.9)
#pragma unroll
    for (int r = 0; r < 4; ++r) {
        const int qglob = q0 + wid * 16 + l4 * 4 + r;
        const float inv = 1.0f / (li[r] * 0.9f);
        ushort* orow = AO + ((size_t)(b * TSEQ + qglob)) * CDIM + h * HDIM;
#pragma unroll
        for (int dt = 0; dt < 4; ++dt)
            orow[dt * 16 + l15] = f2bf(oacc[dt][r] * inv);
    }
}

// ---------------------------------------------------------------------------
extern "C" void kernel_launch(void* const* d_in, const int* in_sizes, int n_in,
                              void* d_out, int out_size, void* d_ws, size_t ws_size,
                              hipStream_t stream)
{
    const float* x      = (const float*)d_in[0];
    const float* w_attn = (const float*)d_in[1];
    const float* b_attn = (const float*)d_in[2];
    const float* w_proj = (const float*)d_in[3];
    const float* b_proj = (const float*)d_in[4];
    float* out = (float*)d_out;

    const size_t NH = (size_t)NBATCH * NHEAD * TSEQ * HDIM;   // 4,194,304
    ushort* Qb  = (ushort*)d_ws;
    ushort* Kb  = Qb + NH;
    ushort* Vb  = Kb + NH;
    ushort* AO  = Vb + NH;                  // bf16 [B,T,C]
    ushort* xb  = AO + NH;                  // bf16 [4096][1024]
    ushort* wTa = xb + NH;                  // bf16 [3072][1024]
    ushort* wTp = wTa + (size_t)3072 * 1024;// bf16 [1024][1024]

    cvt_bf16<<<2048, 256, 0, stream>>>(x, xb, 4096 * 1024);
    transpose_cvt<<<dim3(96, 32), 256, 0, stream>>>(w_attn, wTa, 1024, 3072);
    transpose_cvt<<<dim3(32, 32), 256, 0, stream>>>(w_proj, wTp, 1024, 1024);

    gemm_bf16<1><<<dim3(24, 32), 256, 0, stream>>>(
        xb, wTa, b_attn, Qb, Kb, Vb, nullptr, 4096, 3072, 1024);

    attn_fwd_mfma<<<dim3(TSEQ / 64, NHEAD, NBATCH), 256, 0, stream>>>(Qb, Kb, Vb, AO);

    gemm_bf16<0><<<dim3(8, 32), 256, 0, stream>>>(
        AO, wTp, b_proj, nullptr, nullptr, nullptr, out, 4096, 1024, 1024);
}

// Round 4
// 249.698 us; speedup vs baseline: 36.0035x; 1.7307x over previous
//
#include <hip/hip_runtime.h>
#include <hip/hip_bf16.h>
#include <stdint.h>
#include <math.h>

#define TSEQ   2048
#define NBATCH 2
#define NHEAD  16
#define HDIM   64
#define CDIM   1024

// keep iff uniform(bits) < f32(0.9)  <=>  (bits>>9) < 7549747
#define KEEP_THRESH 7549747u

typedef short  bf16x8 __attribute__((ext_vector_type(8)));
typedef float  f32x4  __attribute__((ext_vector_type(4)));

// ---------------------------------------------------------------------------
// threefry2x32, key (0,42), 20 rounds; returns y0 ^ y1 (JAX partitionable).
// ---------------------------------------------------------------------------
__device__ __forceinline__ uint32_t rotl32(uint32_t x, int r) {
    return __builtin_amdgcn_alignbit(x, x, 32 - r);   // 1-inst rotate
}

__device__ __forceinline__ uint32_t tf2x32_xor(uint32_t x0, uint32_t x1) {
    const uint32_t ka = 0u, kb = 42u;
    const uint32_t kc = ka ^ kb ^ 0x1BD11BDAu;
    x0 += ka; x1 += kb;
#define TFR(r) { x0 += x1; x1 = rotl32(x1, r); x1 ^= x0; }
    TFR(13) TFR(15) TFR(26) TFR(6)
    x0 += kb; x1 += kc + 1u;
    TFR(17) TFR(29) TFR(16) TFR(24)
    x0 += kc; x1 += ka + 2u;
    TFR(13) TFR(15) TFR(26) TFR(6)
    x0 += ka; x1 += kb + 3u;
    TFR(17) TFR(29) TFR(16) TFR(24)
    x0 += kb; x1 += kc + 4u;
    TFR(13) TFR(15) TFR(26) TFR(6)
    x0 += kc; x1 += ka + 5u;
#undef TFR
    return x0 ^ x1;
}

__device__ __forceinline__ bool tf_keep(uint32_t idx) {
    return (tf2x32_xor(0u, idx) >> 9) < KEEP_THRESH;
}

__device__ __forceinline__ ushort f2bf(float f) {
    __hip_bfloat16 h = __float2bfloat16(f);
    return *reinterpret_cast<ushort*>(&h);
}

__device__ __forceinline__ void async_copy16(void* lds, const void* g) {
    __builtin_amdgcn_global_load_lds(
        (const __attribute__((address_space(1))) unsigned int*)g,
        (__attribute__((address_space(3))) unsigned int*)lds, 16, 0, 0);
}

// ---------------------------------------------------------------------------
// x f32 -> bf16 (same layout), 8 elems/thread
// ---------------------------------------------------------------------------
__global__ __launch_bounds__(256) void cvt_bf16(
    const float* __restrict__ src, ushort* __restrict__ dst, int n)
{
    int idx = (blockIdx.x * 256 + threadIdx.x) * 8;
    if (idx >= n) return;
    float4 a = *(const float4*)(src + idx);
    float4 b = *(const float4*)(src + idx + 4);
    ushort4 o1; o1.x = f2bf(a.x); o1.y = f2bf(a.y); o1.z = f2bf(a.z); o1.w = f2bf(a.w);
    ushort4 o2; o2.x = f2bf(b.x); o2.y = f2bf(b.y); o2.z = f2bf(b.z); o2.w = f2bf(b.w);
    *(ushort4*)(dst + idx) = o1;
    *(ushort4*)(dst + idx + 4) = o2;
}

// ---------------------------------------------------------------------------
// w f32 [K][N] -> bf16 [N][K]  (32x32 LDS tiles)
// ---------------------------------------------------------------------------
__global__ __launch_bounds__(256) void transpose_cvt(
    const float* __restrict__ src, ushort* __restrict__ dst, int K, int N)
{
    __shared__ float t[32][33];
    const int n0 = blockIdx.x * 32, k0 = blockIdx.y * 32;
    const int i = threadIdx.x;
    {
        int k = i >> 3, n4 = (i & 7) * 4;
        float4 v = *(const float4*)(src + (size_t)(k0 + k) * N + n0 + n4);
        t[k][n4 + 0] = v.x; t[k][n4 + 1] = v.y; t[k][n4 + 2] = v.z; t[k][n4 + 3] = v.w;
    }
    __syncthreads();
    {
        int n = i >> 3, k4 = (i & 7) * 4;
        ushort4 o;
        o.x = f2bf(t[k4 + 0][n]); o.y = f2bf(t[k4 + 1][n]);
        o.z = f2bf(t[k4 + 2][n]); o.w = f2bf(t[k4 + 3][n]);
        *(ushort4*)(dst + (size_t)(n0 + n) * K + k0 + k4) = o;
    }
}

// ---------------------------------------------------------------------------
// bf16 MFMA GEMM: C[M][N] = A[M][K] * Bt[N][K]^T + bias
// 128x128 tile, BK=32, 256 thr = 4 waves (2x2), double-buffered LDS.
// MODE 0: C = f32 out.
// MODE 1: scatter bf16 Q,K -> [B,H,T,D]; V -> TRANSPOSED [B,H,D,T].
// ---------------------------------------------------------------------------
template<int MODE>
__global__ __launch_bounds__(256) void gemm_bf16(
    const ushort* __restrict__ A, const ushort* __restrict__ Bt,
    const float* __restrict__ bias,
    ushort* __restrict__ Q, ushort* __restrict__ Kq, ushort* __restrict__ V,
    float* __restrict__ Cf, int M, int N, int K)
{
    __shared__ ushort As[2][128 * 32];
    __shared__ ushort Bs[2][128 * 32];
    const int tid = threadIdx.x, lane = tid & 63, wid = tid >> 6;
    const int l15 = lane & 15, l4 = lane >> 4;
    const int wr = wid >> 1, wc = wid & 1;
    const int bn = blockIdx.x, bm = blockIdx.y;
    const int NTK = K >> 5;

    f32x4 acc[4][4];
#pragma unroll
    for (int m = 0; m < 4; ++m)
#pragma unroll
        for (int n = 0; n < 4; ++n) acc[m][n] = (f32x4){0.f, 0.f, 0.f, 0.f};

    auto stage = [&](int p, int k0) {
#pragma unroll
        for (int j = 0; j < 2; ++j) {
            const int rbase = wid * 32 + j * 16;
            const int row = rbase + (lane >> 2);
            const ushort* src = A + (size_t)(bm * 128 + row) * K + k0 + (lane & 3) * 8;
            async_copy16(&As[p][rbase * 32], src);
        }
#pragma unroll
        for (int j = 0; j < 2; ++j) {
            const int rbase = wid * 32 + j * 16;
            const int row = rbase + (lane >> 2);
            const ushort* src = Bt + (size_t)(bn * 128 + row) * K + k0 + (lane & 3) * 8;
            async_copy16(&Bs[p][rbase * 32], src);
        }
    };
    auto compute = [&](int p) {
        bf16x8 af[4], bf[4];
#pragma unroll
        for (int m = 0; m < 4; ++m)
            af[m] = *(const bf16x8*)&As[p][(wr * 64 + m * 16 + l15) * 32 + l4 * 8];
#pragma unroll
        for (int n = 0; n < 4; ++n)
            bf[n] = *(const bf16x8*)&Bs[p][(wc * 64 + n * 16 + l15) * 32 + l4 * 8];
#pragma unroll
        for (int m = 0; m < 4; ++m)
#pragma unroll
            for (int n = 0; n < 4; ++n)
                acc[m][n] = __builtin_amdgcn_mfma_f32_16x16x32_bf16(af[m], bf[n], acc[m][n], 0, 0, 0);
    };

    stage(0, 0);
    __syncthreads();
    for (int t = 0; t < NTK; ++t) {
        const int p = t & 1;
        if (t + 1 < NTK) stage(p ^ 1, (t + 1) << 5);
        compute(p);
        __syncthreads();
    }

    const int colbase = bn * 128 + wc * 64;
    const int rowbase = bm * 128 + wr * 64;
    if (MODE == 0) {
#pragma unroll
        for (int n = 0; n < 4; ++n) {
            const int col = colbase + n * 16 + l15;
            const float bv = bias[col];
#pragma unroll
            for (int m = 0; m < 4; ++m)
#pragma unroll
                for (int r = 0; r < 4; ++r) {
                    const int row = rowbase + m * 16 + l4 * 4 + r;
                    Cf[(size_t)row * N + col] = acc[m][n][r] + bv;
                }
        }
    } else {
#pragma unroll
        for (int n = 0; n < 4; ++n) {
            const int col = colbase + n * 16 + l15;
            const int which = col >> 10, cc = col & 1023;
            const int hh = cc >> 6, dd = cc & 63;
            const float bv = bias[col];
#pragma unroll
            for (int m = 0; m < 4; ++m)
#pragma unroll
                for (int r = 0; r < 4; ++r) {
                    const int row = rowbase + m * 16 + l4 * 4 + r;
                    const int bb = row >> 11, tt = row & 2047;
                    const ushort val = f2bf(acc[m][n][r] + bv);
                    if (which == 0)
                        Q[(((size_t)(bb * NHEAD + hh)) * TSEQ + tt) * HDIM + dd] = val;
                    else if (which == 1)
                        Kq[(((size_t)(bb * NHEAD + hh)) * TSEQ + tt) * HDIM + dd] = val;
                    else
                        V[(((size_t)(bb * NHEAD + hh)) * HDIM + dd) * TSEQ + tt] = val;
                }
        }
    }
}

// ---------------------------------------------------------------------------
// Kernel 2: causal flash attention, bf16 MFMA, exact threefry dropout.
// 256 thr = 4 waves. Mirror-paired q-tiles: block handles qt=p and qt=31-p
// (uniform 33 kv-tiles per block -> perfect load balance across CUs).
// Swapped MFMA operands: S^T = mfma(K,Q) puts one q-row per lane ->
// softmax reduce = 2 shfl (lanes l15,l15+16,+32,+48), mi/li scalars.
// V stored pre-transposed [B,H,D,T] -> staged via async glds like K.
// LDS XOR-swizzle (col8group ^= row&7) on K/V tiles and Ps.
// ---------------------------------------------------------------------------
__global__ __launch_bounds__(256) void attn_fwd_mfma(
    const ushort* __restrict__ Qb, const ushort* __restrict__ Kb,
    const ushort* __restrict__ VbT, ushort* __restrict__ AO)
{
    __shared__ ushort Ks[2][64 * 64];
    __shared__ ushort Vt[2][64 * 64];
    __shared__ ushort Ps[64 * 64];
    const int tid = threadIdx.x;
    const int lane = tid & 63;
    const int wid = tid >> 6;
    const int l15 = lane & 15, l4 = lane >> 4;
    const int h = blockIdx.y, b = blockIdx.z;
    const int hb = b * NHEAD + h;
    const size_t headoff = (size_t)hb * TSEQ * HDIM;
    const ushort* Qg = Qb + headoff;
    const ushort* Kg = Kb + headoff;
    const ushort* Vg = VbT + headoff;   // [D][T] rows

    auto stage = [&](int p, int kt) {
        const ushort* Kt = Kg + (size_t)(kt * 64) * HDIM;
        const ushort* Vt0 = Vg + kt * 64;
#pragma unroll
        for (int c = 0; c < 2; ++c) {
            const int rbase = wid * 16 + c * 8;     // wave-uniform
            const int row = rbase + (lane >> 3);
            const ushort* srcK = Kt + row * 64 + (((lane & 7) * 8) ^ ((row & 7) << 3));
            async_copy16(&Ks[p][rbase * 64], srcK);
            const ushort* srcV = Vt0 + (size_t)row * TSEQ + (((lane & 7) * 8) ^ ((row & 7) << 3));
            async_copy16(&Vt[p][rbase * 64], srcV);
        }
    };

    const int swq = (l15 & 7) << 3;          // Ps swizzle (row = own q = l15)
    const int prow = wid * 16 + l15;

    for (int pass = 0; pass < 2; ++pass) {
        const int qt = pass ? (TSEQ / 64 - 1) - (int)blockIdx.x : (int)blockIdx.x;
        const int q0 = qt * 64;
        const int qglob = q0 + wid * 16 + l15;   // this thread's q row

        // Q fragments (B-operand: col=q=l15, k=d)
        bf16x8 qf0, qf1;
        {
            const ushort* qrow = Qg + (size_t)qglob * HDIM;
            qf0 = *(const bf16x8*)(qrow + l4 * 8);
            qf1 = *(const bf16x8*)(qrow + 32 + l4 * 8);
        }

        f32x4 oacc[4];
#pragma unroll
        for (int i = 0; i < 4; ++i) oacc[i] = (f32x4){0.f, 0.f, 0.f, 0.f};
        float mi = -INFINITY, li = 0.f;
        const uint32_t rowbase = ((uint32_t)hb * TSEQ + (uint32_t)qglob) * TSEQ;

        stage(0, 0);
        __syncthreads();

        for (int kt = 0; kt <= qt; ++kt) {
            const int p = kt & 1;
            if (kt < qt) stage(p ^ 1, kt + 1);

            // ---- S^T = mfma(K, Q): D[col=q=l15][row=k=l4*4+r]
            f32x4 s4[4];
#pragma unroll
            for (int ct = 0; ct < 4; ++ct) {
                const int krow = ct * 16 + l15;
                const int sw = (krow & 7) << 3;
                bf16x8 kf0 = *(const bf16x8*)&Ks[p][krow * 64 + ((l4 * 8) ^ sw)];
                bf16x8 kf1 = *(const bf16x8*)&Ks[p][krow * 64 + ((l4 * 8 + 32) ^ sw)];
                f32x4 a = {0.f, 0.f, 0.f, 0.f};
                a = __builtin_amdgcn_mfma_f32_16x16x32_bf16(kf0, qf0, a, 0, 0, 0);
                a = __builtin_amdgcn_mfma_f32_16x16x32_bf16(kf1, qf1, a, 0, 0, 0);
                s4[ct] = a;
            }

            // ---- per-thread row softmax (16 k-entries for q=l15)
            const int kb0 = kt * 64;
            float ev[4][4];
            float mx = -INFINITY;
#pragma unroll
            for (int ct = 0; ct < 4; ++ct)
#pragma unroll
                for (int r = 0; r < 4; ++r) {
                    const int kglob = kb0 + ct * 16 + l4 * 4 + r;
                    const float xx = s4[ct][r] * 0.125f;
                    ev[ct][r] = (kglob <= qglob) ? xx : -INFINITY;
                    mx = fmaxf(mx, ev[ct][r]);
                }
            mx = fmaxf(mx, __shfl_xor(mx, 16));
            mx = fmaxf(mx, __shfl_xor(mx, 32));
            const float mnew = fmaxf(mi, mx);
            const float alpha = __expf(mi - mnew);
            mi = mnew;
            float rs = 0.f;
#pragma unroll
            for (int ct = 0; ct < 4; ++ct)
#pragma unroll
                for (int r = 0; r < 4; ++r) {
                    ev[ct][r] = __expf(ev[ct][r] - mnew);
                    rs += ev[ct][r];
                }
            rs += __shfl_xor(rs, 16);
            rs += __shfl_xor(rs, 32);
            li = li * alpha + rs;
#pragma unroll
            for (int dt = 0; dt < 4; ++dt) {
                oacc[dt][0] *= alpha; oacc[dt][1] *= alpha;
                oacc[dt][2] *= alpha; oacc[dt][3] *= alpha;
            }

            // ---- exact threefry dropout + P -> Ps (bf16, own row, b64 writes)
            const uint32_t idx0 = rowbase + (uint32_t)kb0;
#pragma unroll
            for (int ct = 0; ct < 4; ++ct) {
                const uint32_t kk = idx0 + (uint32_t)(ct * 16 + l4 * 4);
                ushort4 pk;
                pk.x = f2bf(tf_keep(kk + 0u) ? ev[ct][0] : 0.f);
                pk.y = f2bf(tf_keep(kk + 1u) ? ev[ct][1] : 0.f);
                pk.z = f2bf(tf_keep(kk + 2u) ? ev[ct][2] : 0.f);
                pk.w = f2bf(tf_keep(kk + 3u) ? ev[ct][3] : 0.f);
                *(ushort4*)&Ps[prow * 64 + ((ct * 16 + l4 * 4) ^ swq)] = pk;
            }

            // ---- O^T += mfma(V^T, P): A=V^T[d][k], B=P[q][k]
            bf16x8 pf0 = *(const bf16x8*)&Ps[prow * 64 + ((l4 * 8) ^ swq)];
            bf16x8 pf1 = *(const bf16x8*)&Ps[prow * 64 + ((l4 * 8 + 32) ^ swq)];
#pragma unroll
            for (int dt = 0; dt < 4; ++dt) {
                const int drow = dt * 16 + l15;
                const int swv = (drow & 7) << 3;
                bf16x8 vf0 = *(const bf16x8*)&Vt[p][drow * 64 + ((l4 * 8) ^ swv)];
                bf16x8 vf1 = *(const bf16x8*)&Vt[p][drow * 64 + ((l4 * 8 + 32) ^ swv)];
                oacc[dt] = __builtin_amdgcn_mfma_f32_16x16x32_bf16(vf0, pf0, oacc[dt], 0, 0, 0);
                oacc[dt] = __builtin_amdgcn_mfma_f32_16x16x32_bf16(vf1, pf1, oacc[dt], 0, 0, 0);
            }
            __syncthreads();   // drains glds for kt+1; guards buffer reuse
        }

        // ---- epilogue: AO[q][h*64+d] = oacc / (li*0.9); d = dt*16+l4*4+r
        const float inv = 1.0f / (li * 0.9f);
        ushort* orow = AO + ((size_t)(b * TSEQ + qglob)) * CDIM + h * HDIM;
#pragma unroll
        for (int dt = 0; dt < 4; ++dt) {
            ushort4 o;
            o.x = f2bf(oacc[dt][0] * inv);
            o.y = f2bf(oacc[dt][1] * inv);
            o.z = f2bf(oacc[dt][2] * inv);
            o.w = f2bf(oacc[dt][3] * inv);
            *(ushort4*)&orow[dt * 16 + l4 * 4] = o;
        }
        __syncthreads();   // pass isolation before re-staging buffer 0
    }
}

// ---------------------------------------------------------------------------
extern "C" void kernel_launch(void* const* d_in, const int* in_sizes, int n_in,
                              void* d_out, int out_size, void* d_ws, size_t ws_size,
                              hipStream_t stream)
{
    const float* x      = (const float*)d_in[0];
    const float* w_attn = (const float*)d_in[1];
    const float* b_attn = (const float*)d_in[2];
    const float* w_proj = (const float*)d_in[3];
    const float* b_proj = (const float*)d_in[4];
    float* out = (float*)d_out;

    const size_t NH = (size_t)NBATCH * NHEAD * TSEQ * HDIM;   // 4,194,304
    ushort* Qb  = (ushort*)d_ws;
    ushort* Kb  = Qb + NH;
    ushort* VbT = Kb + NH;                  // bf16 [B,H,D,T]
    ushort* AO  = VbT + NH;                 // bf16 [B,T,C]
    ushort* xb  = AO + NH;                  // bf16 [4096][1024]
    ushort* wTa = xb + NH;                  // bf16 [3072][1024]
    ushort* wTp = wTa + (size_t)3072 * 1024;// bf16 [1024][1024]

    cvt_bf16<<<2048, 256, 0, stream>>>(x, xb, 4096 * 1024);
    transpose_cvt<<<dim3(96, 32), 256, 0, stream>>>(w_attn, wTa, 1024, 3072);
    transpose_cvt<<<dim3(32, 32), 256, 0, stream>>>(w_proj, wTp, 1024, 1024);

    gemm_bf16<1><<<dim3(24, 32), 256, 0, stream>>>(
        xb, wTa, b_attn, Qb, Kb, VbT, nullptr, 4096, 3072, 1024);

    attn_fwd_mfma<<<dim3(TSEQ / 128, NHEAD, NBATCH), 256, 0, stream>>>(Qb, Kb, VbT, AO);

    gemm_bf16<0><<<dim3(8, 32), 256, 0, stream>>>(
        AO, wTp, b_proj, nullptr, nullptr, nullptr, out, 4096, 1024, 1024);
}

// Round 5
// 247.134 us; speedup vs baseline: 36.3770x; 1.0104x over previous
//
#include <hip/hip_runtime.h>
#include <hip/hip_bf16.h>
#include <stdint.h>
#include <math.h>

#define TSEQ   2048
#define NBATCH 2
#define NHEAD  16
#define HDIM   64
#define CDIM   1024

// keep iff uniform(bits) < f32(0.9)  <=>  (bits>>9) < 7549747
#define KEEP_THRESH 7549747u
// 0.125 (1/sqrt(64)) * log2(e): S' = S*QSC so softmax runs in exp2 domain
#define QSC 0.18033688011112042f

typedef short  bf16x8 __attribute__((ext_vector_type(8)));
typedef float  f32x4  __attribute__((ext_vector_type(4)));

// ---------------------------------------------------------------------------
// threefry2x32, key (0,42), 20 rounds; returns y0 ^ y1 (JAX partitionable).
// ---------------------------------------------------------------------------
__device__ __forceinline__ uint32_t rotl32(uint32_t x, int r) {
    return __builtin_amdgcn_alignbit(x, x, 32 - r);   // 1-inst rotate
}

__device__ __forceinline__ uint32_t tf2x32_xor(uint32_t x0, uint32_t x1) {
    const uint32_t ka = 0u, kb = 42u;
    const uint32_t kc = ka ^ kb ^ 0x1BD11BDAu;
    x0 += ka; x1 += kb;
#define TFR(r) { x0 += x1; x1 = rotl32(x1, r); x1 ^= x0; }
    TFR(13) TFR(15) TFR(26) TFR(6)
    x0 += kb; x1 += kc + 1u;
    TFR(17) TFR(29) TFR(16) TFR(24)
    x0 += kc; x1 += ka + 2u;
    TFR(13) TFR(15) TFR(26) TFR(6)
    x0 += ka; x1 += kb + 3u;
    TFR(17) TFR(29) TFR(16) TFR(24)
    x0 += kb; x1 += kc + 4u;
    TFR(13) TFR(15) TFR(26) TFR(6)
    x0 += kc; x1 += ka + 5u;
#undef TFR
    return x0 ^ x1;
}

__device__ __forceinline__ bool tf_keep(uint32_t idx) {
    return (tf2x32_xor(0u, idx) >> 9) < KEEP_THRESH;
}

__device__ __forceinline__ ushort f2bf(float f) {
    __hip_bfloat16 h = __float2bfloat16(f);
    return *reinterpret_cast<ushort*>(&h);
}

__device__ __forceinline__ float bf2f(ushort u) {
    union { uint32_t i; float f; } c; c.i = ((uint32_t)u) << 16; return c.f;
}

__device__ __forceinline__ void async_copy16(void* lds, const void* g) {
    __builtin_amdgcn_global_load_lds(
        (const __attribute__((address_space(1))) unsigned int*)g,
        (__attribute__((address_space(3))) unsigned int*)lds, 16, 0, 0);
}

// ---------------------------------------------------------------------------
// x f32 -> bf16 (same layout), 8 elems/thread
// ---------------------------------------------------------------------------
__global__ __launch_bounds__(256) void cvt_bf16(
    const float* __restrict__ src, ushort* __restrict__ dst, int n)
{
    int idx = (blockIdx.x * 256 + threadIdx.x) * 8;
    if (idx >= n) return;
    float4 a = *(const float4*)(src + idx);
    float4 b = *(const float4*)(src + idx + 4);
    ushort4 o1; o1.x = f2bf(a.x); o1.y = f2bf(a.y); o1.z = f2bf(a.z); o1.w = f2bf(a.w);
    ushort4 o2; o2.x = f2bf(b.x); o2.y = f2bf(b.y); o2.z = f2bf(b.z); o2.w = f2bf(b.w);
    *(ushort4*)(dst + idx) = o1;
    *(ushort4*)(dst + idx + 4) = o2;
}

// ---------------------------------------------------------------------------
// w f32 [K][N] -> bf16 [N][K]  (32x32 LDS tiles)
// ---------------------------------------------------------------------------
__global__ __launch_bounds__(256) void transpose_cvt(
    const float* __restrict__ src, ushort* __restrict__ dst, int K, int N)
{
    __shared__ float t[32][33];
    const int n0 = blockIdx.x * 32, k0 = blockIdx.y * 32;
    const int i = threadIdx.x;
    {
        int k = i >> 3, n4 = (i & 7) * 4;
        float4 v = *(const float4*)(src + (size_t)(k0 + k) * N + n0 + n4);
        t[k][n4 + 0] = v.x; t[k][n4 + 1] = v.y; t[k][n4 + 2] = v.z; t[k][n4 + 3] = v.w;
    }
    __syncthreads();
    {
        int n = i >> 3, k4 = (i & 7) * 4;
        ushort4 o;
        o.x = f2bf(t[k4 + 0][n]); o.y = f2bf(t[k4 + 1][n]);
        o.z = f2bf(t[k4 + 2][n]); o.w = f2bf(t[k4 + 3][n]);
        *(ushort4*)(dst + (size_t)(n0 + n) * K + k0 + k4) = o;
    }
}

// ---------------------------------------------------------------------------
// bf16 MFMA GEMM: C[M][N] = A[M][K] * Bt[N][K]^T + bias
// 128x128 tile, BK=32, 256 thr = 4 waves (2x2), double-buffered LDS.
// MODE 0: C = f32 out.
// MODE 1: scatter bf16 Q (pre-scaled by QSC), K -> [B,H,T,D]; V -> [B,H,D,T].
// ---------------------------------------------------------------------------
template<int MODE>
__global__ __launch_bounds__(256) void gemm_bf16(
    const ushort* __restrict__ A, const ushort* __restrict__ Bt,
    const float* __restrict__ bias,
    ushort* __restrict__ Q, ushort* __restrict__ Kq, ushort* __restrict__ V,
    float* __restrict__ Cf, int M, int N, int K)
{
    __shared__ ushort As[2][128 * 32];
    __shared__ ushort Bs[2][128 * 32];
    const int tid = threadIdx.x, lane = tid & 63, wid = tid >> 6;
    const int l15 = lane & 15, l4 = lane >> 4;
    const int wr = wid >> 1, wc = wid & 1;
    const int bn = blockIdx.x, bm = blockIdx.y;
    const int NTK = K >> 5;

    f32x4 acc[4][4];
#pragma unroll
    for (int m = 0; m < 4; ++m)
#pragma unroll
        for (int n = 0; n < 4; ++n) acc[m][n] = (f32x4){0.f, 0.f, 0.f, 0.f};

    auto stage = [&](int p, int k0) {
#pragma unroll
        for (int j = 0; j < 2; ++j) {
            const int rbase = wid * 32 + j * 16;
            const int row = rbase + (lane >> 2);
            const ushort* src = A + (size_t)(bm * 128 + row) * K + k0 + (lane & 3) * 8;
            async_copy16(&As[p][rbase * 32], src);
        }
#pragma unroll
        for (int j = 0; j < 2; ++j) {
            const int rbase = wid * 32 + j * 16;
            const int row = rbase + (lane >> 2);
            const ushort* src = Bt + (size_t)(bn * 128 + row) * K + k0 + (lane & 3) * 8;
            async_copy16(&Bs[p][rbase * 32], src);
        }
    };
    auto compute = [&](int p) {
        bf16x8 af[4], bf[4];
#pragma unroll
        for (int m = 0; m < 4; ++m)
            af[m] = *(const bf16x8*)&As[p][(wr * 64 + m * 16 + l15) * 32 + l4 * 8];
#pragma unroll
        for (int n = 0; n < 4; ++n)
            bf[n] = *(const bf16x8*)&Bs[p][(wc * 64 + n * 16 + l15) * 32 + l4 * 8];
#pragma unroll
        for (int m = 0; m < 4; ++m)
#pragma unroll
            for (int n = 0; n < 4; ++n)
                acc[m][n] = __builtin_amdgcn_mfma_f32_16x16x32_bf16(af[m], bf[n], acc[m][n], 0, 0, 0);
    };

    stage(0, 0);
    __syncthreads();
    for (int t = 0; t < NTK; ++t) {
        const int p = t & 1;
        if (t + 1 < NTK) stage(p ^ 1, (t + 1) << 5);
        compute(p);
        __syncthreads();
    }

    const int colbase = bn * 128 + wc * 64;
    const int rowbase = bm * 128 + wr * 64;
    if (MODE == 0) {
#pragma unroll
        for (int n = 0; n < 4; ++n) {
            const int col = colbase + n * 16 + l15;
            const float bv = bias[col];
#pragma unroll
            for (int m = 0; m < 4; ++m)
#pragma unroll
                for (int r = 0; r < 4; ++r) {
                    const int row = rowbase + m * 16 + l4 * 4 + r;
                    Cf[(size_t)row * N + col] = acc[m][n][r] + bv;
                }
        }
    } else {
#pragma unroll
        for (int n = 0; n < 4; ++n) {
            const int col = colbase + n * 16 + l15;
            const int which = col >> 10, cc = col & 1023;
            const int hh = cc >> 6, dd = cc & 63;
            const float bv = bias[col];
            const float sc = (which == 0) ? QSC : 1.0f;
#pragma unroll
            for (int m = 0; m < 4; ++m)
#pragma unroll
                for (int r = 0; r < 4; ++r) {
                    const int row = rowbase + m * 16 + l4 * 4 + r;
                    const int bb = row >> 11, tt = row & 2047;
                    const ushort val = f2bf((acc[m][n][r] + bv) * sc);
                    if (which == 0)
                        Q[(((size_t)(bb * NHEAD + hh)) * TSEQ + tt) * HDIM + dd] = val;
                    else if (which == 1)
                        Kq[(((size_t)(bb * NHEAD + hh)) * TSEQ + tt) * HDIM + dd] = val;
                    else
                        V[(((size_t)(bb * NHEAD + hh)) * HDIM + dd) * TSEQ + tt] = val;
                }
        }
    }
}

// ---------------------------------------------------------------------------
// Kernel 2: causal flash attention partials, bf16 MFMA, exact threefry drop.
// Grid x: 32 = {pair 0..15} x {half 0..1}; per pass qt = pair / 31-pair.
// Each block computes a PARTIAL flash pass over its half of the kv range:
// A (unnormalized PV, bf16) -> Ap, row-max m and row-sum l -> mp/lp.
// 1024 uniform blocks (~16.5 kv-tiles each) -> 4 blocks/CU (LDS 40KB).
// Softmax in exp2 domain (Q pre-scaled by QSC in QKV GEMM epilogue).
// ---------------------------------------------------------------------------
__global__ __launch_bounds__(256) void attn_fwd_mfma(
    const ushort* __restrict__ Qb, const ushort* __restrict__ Kb,
    const ushort* __restrict__ VbT,
    ushort* __restrict__ Ap, float* __restrict__ mp, float* __restrict__ lp)
{
    __shared__ ushort Ks[2][64 * 64];
    __shared__ ushort Vt[2][64 * 64];
    __shared__ ushort Ps[64 * 64];
    const int tid = threadIdx.x;
    const int lane = tid & 63;
    const int wid = tid >> 6;
    const int l15 = lane & 15, l4 = lane >> 4;
    const int pair = blockIdx.x >> 1, half = blockIdx.x & 1;
    const int h = blockIdx.y, b = blockIdx.z;
    const int hb = b * NHEAD + h;
    const size_t headoff = (size_t)hb * TSEQ * HDIM;
    const ushort* Qg = Qb + headoff;
    const ushort* Kg = Kb + headoff;
    const ushort* Vg = VbT + headoff;   // [D][T] rows

    auto stage = [&](int p, int kt) {
        const ushort* Kt = Kg + (size_t)(kt * 64) * HDIM;
        const ushort* Vt0 = Vg + kt * 64;
#pragma unroll
        for (int c = 0; c < 2; ++c) {
            const int rbase = wid * 16 + c * 8;     // wave-uniform
            const int row = rbase + (lane >> 3);
            const ushort* srcK = Kt + row * 64 + (((lane & 7) * 8) ^ ((row & 7) << 3));
            async_copy16(&Ks[p][rbase * 64], srcK);
            const ushort* srcV = Vt0 + (size_t)row * TSEQ + (((lane & 7) * 8) ^ ((row & 7) << 3));
            async_copy16(&Vt[p][rbase * 64], srcV);
        }
    };

    const int swq = (l15 & 7) << 3;          // Ps swizzle (row = own q = l15)
    const int prow = wid * 16 + l15;

    for (int pass = 0; pass < 2; ++pass) {
        const int qt = pass ? (TSEQ / 64 - 1) - pair : pair;
        const int ntk = qt + 1;
        const int kb = half ? (ntk + 1) >> 1 : 0;
        const int ke = half ? ntk : (ntk + 1) >> 1;
        const int pidx = (hb * 32 + qt) * 2 + half;
        const int tilerow = wid * 16 + l15;
        ushort* arow = Ap + (size_t)pidx * 4096 + tilerow * 64;

        if (kb >= ke) {   // empty half (qt=0, half=1): neutral partial
#pragma unroll
            for (int dt = 0; dt < 4; ++dt) {
                ushort4 z; z.x = z.y = z.z = z.w = 0;
                *(ushort4*)&arow[dt * 16 + l4 * 4] = z;
            }
            if (l4 == 0) { mp[pidx * 64 + tilerow] = -INFINITY; lp[pidx * 64 + tilerow] = 0.f; }
            continue;
        }

        const int qglob = qt * 64 + tilerow;   // this thread's q row
        // Q fragments (B-operand: col=q=l15, k=d); Q is pre-scaled by QSC
        bf16x8 qf0, qf1;
        {
            const ushort* qrow = Qg + (size_t)qglob * HDIM;
            qf0 = *(const bf16x8*)(qrow + l4 * 8);
            qf1 = *(const bf16x8*)(qrow + 32 + l4 * 8);
        }

        f32x4 oacc[4];
#pragma unroll
        for (int i = 0; i < 4; ++i) oacc[i] = (f32x4){0.f, 0.f, 0.f, 0.f};
        float mi = -INFINITY, li = 0.f;
        const uint32_t rowbase = ((uint32_t)hb * TSEQ + (uint32_t)qglob) * TSEQ;

        stage(0, kb);
        __syncthreads();

        for (int kt = kb; kt < ke; ++kt) {
            const int p = (kt - kb) & 1;
            if (kt + 1 < ke) stage(p ^ 1, kt + 1);

            // ---- S^T = mfma(K, Q): lane holds q-row qglob, k = ct*16+l4*4+r
            f32x4 s4[4];
#pragma unroll
            for (int ct = 0; ct < 4; ++ct) {
                const int krow = ct * 16 + l15;
                const int sw = (krow & 7) << 3;
                bf16x8 kf0 = *(const bf16x8*)&Ks[p][krow * 64 + ((l4 * 8) ^ sw)];
                bf16x8 kf1 = *(const bf16x8*)&Ks[p][krow * 64 + ((l4 * 8 + 32) ^ sw)];
                f32x4 a = {0.f, 0.f, 0.f, 0.f};
                a = __builtin_amdgcn_mfma_f32_16x16x32_bf16(kf0, qf0, a, 0, 0, 0);
                a = __builtin_amdgcn_mfma_f32_16x16x32_bf16(kf1, qf1, a, 0, 0, 0);
                s4[ct] = a;
            }

            // ---- per-thread row softmax, exp2 domain
            const int kb0 = kt * 64;
            float ev[4][4];
            float mx = -INFINITY;
            if (kt == qt) {   // diagonal tile: causal mask
#pragma unroll
                for (int ct = 0; ct < 4; ++ct)
#pragma unroll
                    for (int r = 0; r < 4; ++r) {
                        const int kglob = kb0 + ct * 16 + l4 * 4 + r;
                        ev[ct][r] = (kglob <= qglob) ? s4[ct][r] : -INFINITY;
                        mx = fmaxf(mx, ev[ct][r]);
                    }
            } else {          // full tile: no mask
#pragma unroll
                for (int ct = 0; ct < 4; ++ct)
#pragma unroll
                    for (int r = 0; r < 4; ++r) {
                        ev[ct][r] = s4[ct][r];
                        mx = fmaxf(mx, ev[ct][r]);
                    }
            }
            mx = fmaxf(mx, __shfl_xor(mx, 16));
            mx = fmaxf(mx, __shfl_xor(mx, 32));
            const float mnew = fmaxf(mi, mx);
            const float alpha = exp2f(mi - mnew);
            mi = mnew;
            float rs = 0.f;
#pragma unroll
            for (int ct = 0; ct < 4; ++ct)
#pragma unroll
                for (int r = 0; r < 4; ++r) {
                    ev[ct][r] = exp2f(ev[ct][r] - mnew);
                    rs += ev[ct][r];
                }
            rs += __shfl_xor(rs, 16);
            rs += __shfl_xor(rs, 32);
            li = li * alpha + rs;
#pragma unroll
            for (int dt = 0; dt < 4; ++dt) {
                oacc[dt][0] *= alpha; oacc[dt][1] *= alpha;
                oacc[dt][2] *= alpha; oacc[dt][3] *= alpha;
            }

            // ---- exact threefry dropout + P -> Ps (bf16, own row, b64 writes)
            const uint32_t idx0 = rowbase + (uint32_t)kb0;
#pragma unroll
            for (int ct = 0; ct < 4; ++ct) {
                const uint32_t kk = idx0 + (uint32_t)(ct * 16 + l4 * 4);
                ushort4 pk;
                pk.x = f2bf(tf_keep(kk + 0u) ? ev[ct][0] : 0.f);
                pk.y = f2bf(tf_keep(kk + 1u) ? ev[ct][1] : 0.f);
                pk.z = f2bf(tf_keep(kk + 2u) ? ev[ct][2] : 0.f);
                pk.w = f2bf(tf_keep(kk + 3u) ? ev[ct][3] : 0.f);
                *(ushort4*)&Ps[prow * 64 + ((ct * 16 + l4 * 4) ^ swq)] = pk;
            }

            // ---- A^T += mfma(V^T, P): A-op=V^T[d][k], B-op=P[q][k]
            bf16x8 pf0 = *(const bf16x8*)&Ps[prow * 64 + ((l4 * 8) ^ swq)];
            bf16x8 pf1 = *(const bf16x8*)&Ps[prow * 64 + ((l4 * 8 + 32) ^ swq)];
#pragma unroll
            for (int dt = 0; dt < 4; ++dt) {
                const int drow = dt * 16 + l15;
                const int swv = (drow & 7) << 3;
                bf16x8 vf0 = *(const bf16x8*)&Vt[p][drow * 64 + ((l4 * 8) ^ swv)];
                bf16x8 vf1 = *(const bf16x8*)&Vt[p][drow * 64 + ((l4 * 8 + 32) ^ swv)];
                oacc[dt] = __builtin_amdgcn_mfma_f32_16x16x32_bf16(vf0, pf0, oacc[dt], 0, 0, 0);
                oacc[dt] = __builtin_amdgcn_mfma_f32_16x16x32_bf16(vf1, pf1, oacc[dt], 0, 0, 0);
            }
            __syncthreads();   // drains glds for kt+1; guards buffer reuse
        }

        // ---- partial epilogue: A (bf16, unnormalized), m, l
#pragma unroll
        for (int dt = 0; dt < 4; ++dt) {
            ushort4 o;
            o.x = f2bf(oacc[dt][0]); o.y = f2bf(oacc[dt][1]);
            o.z = f2bf(oacc[dt][2]); o.w = f2bf(oacc[dt][3]);
            *(ushort4*)&arow[dt * 16 + l4 * 4] = o;
        }
        if (l4 == 0) { mp[pidx * 64 + tilerow] = mi; lp[pidx * 64 + tilerow] = li; }
    }
}

// ---------------------------------------------------------------------------
// Kernel 2b: merge the two kv-half partials -> AO bf16 [B,T,C]
// One row (64 d) per 16 threads; 16 rows per 256-thr block.
// ---------------------------------------------------------------------------
__global__ __launch_bounds__(256) void attn_merge(
    const ushort* __restrict__ Ap, const float* __restrict__ mp,
    const float* __restrict__ lp, ushort* __restrict__ AO)
{
    const int gidx = blockIdx.x * 16 + (threadIdx.x >> 4);   // 0..65535
    const int hb = gidx >> 11;          // b*16+h
    const int q  = gidx & 2047;
    const int qt = q >> 6, row = q & 63;
    const int sub = (threadIdx.x & 15) * 4;
    const int pidx0 = (hb * 32 + qt) * 2;
    const int pr = pidx0 * 64 + row;
    const float m0 = mp[pr], m1 = mp[pr + 64];
    const float l0 = lp[pr], l1 = lp[pr + 64];
    const float m  = fmaxf(m0, m1);
    const float w0 = exp2f(m0 - m), w1 = exp2f(m1 - m);
    const float inv = 1.0f / ((l0 * w0 + l1 * w1) * 0.9f);
    const float s0 = w0 * inv, s1 = w1 * inv;
    ushort4 a0 = *(const ushort4*)&Ap[(size_t)pidx0 * 4096 + row * 64 + sub];
    ushort4 a1 = *(const ushort4*)&Ap[(size_t)(pidx0 + 1) * 4096 + row * 64 + sub];
    const int b = hb >> 4, h = hb & 15;
    ushort* orow = AO + ((size_t)(b * TSEQ + q)) * CDIM + h * HDIM + sub;
    ushort4 o;
    o.x = f2bf(bf2f(a0.x) * s0 + bf2f(a1.x) * s1);
    o.y = f2bf(bf2f(a0.y) * s0 + bf2f(a1.y) * s1);
    o.z = f2bf(bf2f(a0.z) * s0 + bf2f(a1.z) * s1);
    o.w = f2bf(bf2f(a0.w) * s0 + bf2f(a1.w) * s1);
    *(ushort4*)orow = o;
}

// ---------------------------------------------------------------------------
extern "C" void kernel_launch(void* const* d_in, const int* in_sizes, int n_in,
                              void* d_out, int out_size, void* d_ws, size_t ws_size,
                              hipStream_t stream)
{
    const float* x      = (const float*)d_in[0];
    const float* w_attn = (const float*)d_in[1];
    const float* b_attn = (const float*)d_in[2];
    const float* w_proj = (const float*)d_in[3];
    const float* b_proj = (const float*)d_in[4];
    float* out = (float*)d_out;

    const size_t NH = (size_t)NBATCH * NHEAD * TSEQ * HDIM;   // 4,194,304
    ushort* Qb  = (ushort*)d_ws;
    ushort* Kb  = Qb + NH;
    ushort* VbT = Kb + NH;                  // bf16 [B,H,D,T]
    ushort* AO  = VbT + NH;                 // bf16 [B,T,C]
    ushort* xb  = AO + NH;                  // bf16 [4096][1024]
    ushort* wTa = xb + NH;                  // bf16 [3072][1024]
    ushort* wTp = wTa + (size_t)3072 * 1024;// bf16 [1024][1024]
    float*  mp  = (float*)(wTp + (size_t)1024 * 1024);  // [2048][64]
    float*  lp  = mp + (size_t)2048 * 64;               // [2048][64]

    // A partials (bf16, 2048 x 64 x 64 = 16.8MB) live in d_out until proj.
    ushort* Aparts = (ushort*)d_out;

    cvt_bf16<<<2048, 256, 0, stream>>>(x, xb, 4096 * 1024);
    transpose_cvt<<<dim3(96, 32), 256, 0, stream>>>(w_attn, wTa, 1024, 3072);
    transpose_cvt<<<dim3(32, 32), 256, 0, stream>>>(w_proj, wTp, 1024, 1024);

    gemm_bf16<1><<<dim3(24, 32), 256, 0, stream>>>(
        xb, wTa, b_attn, Qb, Kb, VbT, nullptr, 4096, 3072, 1024);

    attn_fwd_mfma<<<dim3(32, NHEAD, NBATCH), 256, 0, stream>>>(
        Qb, Kb, VbT, Aparts, mp, lp);

    attn_merge<<<4096, 256, 0, stream>>>(Aparts, mp, lp, AO);

    gemm_bf16<0><<<dim3(8, 32), 256, 0, stream>>>(
        AO, wTp, b_proj, nullptr, nullptr, nullptr, out, 4096, 1024, 1024);
}

// Round 6
// 235.960 us; speedup vs baseline: 38.0997x; 1.0474x over previous
//
#include <hip/hip_runtime.h>
#include <hip/hip_bf16.h>
#include <stdint.h>
#include <math.h>

#define TSEQ   2048
#define NBATCH 2
#define NHEAD  16
#define HDIM   64
#define CDIM   1024

// keep iff uniform(bits) < f32(0.9)  <=>  bits < 7549747*512
#define KEEP_LIMIT 3865470464u
// 0.125 (1/sqrt(64)) * log2(e): S' = S*QSC so softmax runs in exp2 domain
#define QSC 0.18033688011112042f

typedef short  bf16x8 __attribute__((ext_vector_type(8)));
typedef float  f32x4  __attribute__((ext_vector_type(4)));

// ---------------------------------------------------------------------------
// single-inst hardware ops
// ---------------------------------------------------------------------------
__device__ __forceinline__ float fast_exp2(float x) {
    float r; asm("v_exp_f32 %0, %1" : "=v"(r) : "v"(x)); return r;
}
// packed f32x2 -> bf16x2 (low = a, high = b), RNE
__device__ __forceinline__ uint32_t cvt_pk_bf16(float a, float b) {
    uint32_t r; asm("v_cvt_pk_bf16_f32 %0, %1, %2" : "=v"(r) : "v"(a), "v"(b)); return r;
}

// ---------------------------------------------------------------------------
// threefry2x32, key (0,42), 20 rounds; returns y0 ^ y1 (JAX partitionable).
// ---------------------------------------------------------------------------
__device__ __forceinline__ uint32_t rotl32(uint32_t x, int r) {
    return __builtin_amdgcn_alignbit(x, x, 32 - r);   // 1-inst rotate
}

__device__ __forceinline__ uint32_t tf2x32_xor(uint32_t x0, uint32_t x1) {
    const uint32_t ka = 0u, kb = 42u;
    const uint32_t kc = ka ^ kb ^ 0x1BD11BDAu;
    x0 += ka; x1 += kb;
#define TFR(r) { x0 += x1; x1 = rotl32(x1, r); x1 ^= x0; }
    TFR(13) TFR(15) TFR(26) TFR(6)
    x0 += kb; x1 += kc + 1u;
    TFR(17) TFR(29) TFR(16) TFR(24)
    x0 += kc; x1 += ka + 2u;
    TFR(13) TFR(15) TFR(26) TFR(6)
    x0 += ka; x1 += kb + 3u;
    TFR(17) TFR(29) TFR(16) TFR(24)
    x0 += kb; x1 += kc + 4u;
    TFR(13) TFR(15) TFR(26) TFR(6)
    x0 += kc; x1 += ka + 5u;
#undef TFR
    return x0 ^ x1;
}

__device__ __forceinline__ bool tf_keep(uint32_t idx) {
    return tf2x32_xor(0u, idx) < KEEP_LIMIT;
}

__device__ __forceinline__ float bf2f(ushort u) {
    union { uint32_t i; float f; } c; c.i = ((uint32_t)u) << 16; return c.f;
}

__device__ __forceinline__ void async_copy16(void* lds, const void* g) {
    __builtin_amdgcn_global_load_lds(
        (const __attribute__((address_space(1))) unsigned int*)g,
        (__attribute__((address_space(3))) unsigned int*)lds, 16, 0, 0);
}

// ---------------------------------------------------------------------------
// x f32 -> bf16 (same layout), 8 elems/thread
// ---------------------------------------------------------------------------
__global__ __launch_bounds__(256) void cvt_bf16(
    const float* __restrict__ src, ushort* __restrict__ dst, int n)
{
    int idx = (blockIdx.x * 256 + threadIdx.x) * 8;
    if (idx >= n) return;
    float4 a = *(const float4*)(src + idx);
    float4 b = *(const float4*)(src + idx + 4);
    uint4 o;
    o.x = cvt_pk_bf16(a.x, a.y); o.y = cvt_pk_bf16(a.z, a.w);
    o.z = cvt_pk_bf16(b.x, b.y); o.w = cvt_pk_bf16(b.z, b.w);
    *(uint4*)(dst + idx) = o;
}

// ---------------------------------------------------------------------------
// w f32 [K][N] -> bf16 [N][K]  (32x32 LDS tiles)
// ---------------------------------------------------------------------------
__global__ __launch_bounds__(256) void transpose_cvt(
    const float* __restrict__ src, ushort* __restrict__ dst, int K, int N)
{
    __shared__ float t[32][33];
    const int n0 = blockIdx.x * 32, k0 = blockIdx.y * 32;
    const int i = threadIdx.x;
    {
        int k = i >> 3, n4 = (i & 7) * 4;
        float4 v = *(const float4*)(src + (size_t)(k0 + k) * N + n0 + n4);
        t[k][n4 + 0] = v.x; t[k][n4 + 1] = v.y; t[k][n4 + 2] = v.z; t[k][n4 + 3] = v.w;
    }
    __syncthreads();
    {
        int n = i >> 3, k4 = (i & 7) * 4;
        uint2 o;
        o.x = cvt_pk_bf16(t[k4 + 0][n], t[k4 + 1][n]);
        o.y = cvt_pk_bf16(t[k4 + 2][n], t[k4 + 3][n]);
        *(uint2*)(dst + (size_t)(n0 + n) * K + k0 + k4) = o;
    }
}

// ---------------------------------------------------------------------------
// bf16 MFMA GEMM: C[M][N] = A[M][K] * Bt[N][K]^T + bias
// 128x128 tile, BK=32, 256 thr = 4 waves (2x2), double-buffered LDS.
// MODE 0: C = f32 out.
// MODE 1: scatter bf16 Q (pre-scaled by QSC), K -> [B,H,T,D]; V -> [B,H,D,T].
// ---------------------------------------------------------------------------
template<int MODE>
__global__ __launch_bounds__(256) void gemm_bf16(
    const ushort* __restrict__ A, const ushort* __restrict__ Bt,
    const float* __restrict__ bias,
    ushort* __restrict__ Q, ushort* __restrict__ Kq, ushort* __restrict__ V,
    float* __restrict__ Cf, int M, int N, int K)
{
    __shared__ ushort As[2][128 * 32];
    __shared__ ushort Bs[2][128 * 32];
    const int tid = threadIdx.x, lane = tid & 63, wid = tid >> 6;
    const int l15 = lane & 15, l4 = lane >> 4;
    const int wr = wid >> 1, wc = wid & 1;
    const int bn = blockIdx.x, bm = blockIdx.y;
    const int NTK = K >> 5;

    f32x4 acc[4][4];
#pragma unroll
    for (int m = 0; m < 4; ++m)
#pragma unroll
        for (int n = 0; n < 4; ++n) acc[m][n] = (f32x4){0.f, 0.f, 0.f, 0.f};

    auto stage = [&](int p, int k0) {
#pragma unroll
        for (int j = 0; j < 2; ++j) {
            const int rbase = wid * 32 + j * 16;
            const int row = rbase + (lane >> 2);
            const ushort* src = A + (size_t)(bm * 128 + row) * K + k0 + (lane & 3) * 8;
            async_copy16(&As[p][rbase * 32], src);
        }
#pragma unroll
        for (int j = 0; j < 2; ++j) {
            const int rbase = wid * 32 + j * 16;
            const int row = rbase + (lane >> 2);
            const ushort* src = Bt + (size_t)(bn * 128 + row) * K + k0 + (lane & 3) * 8;
            async_copy16(&Bs[p][rbase * 32], src);
        }
    };
    auto compute = [&](int p) {
        bf16x8 af[4], bf[4];
#pragma unroll
        for (int m = 0; m < 4; ++m)
            af[m] = *(const bf16x8*)&As[p][(wr * 64 + m * 16 + l15) * 32 + l4 * 8];
#pragma unroll
        for (int n = 0; n < 4; ++n)
            bf[n] = *(const bf16x8*)&Bs[p][(wc * 64 + n * 16 + l15) * 32 + l4 * 8];
#pragma unroll
        for (int m = 0; m < 4; ++m)
#pragma unroll
            for (int n = 0; n < 4; ++n)
                acc[m][n] = __builtin_amdgcn_mfma_f32_16x16x32_bf16(af[m], bf[n], acc[m][n], 0, 0, 0);
    };

    stage(0, 0);
    __syncthreads();
    for (int t = 0; t < NTK; ++t) {
        const int p = t & 1;
        if (t + 1 < NTK) stage(p ^ 1, (t + 1) << 5);
        compute(p);
        __syncthreads();
    }

    const int colbase = bn * 128 + wc * 64;
    const int rowbase = bm * 128 + wr * 64;
    if (MODE == 0) {
#pragma unroll
        for (int n = 0; n < 4; ++n) {
            const int col = colbase + n * 16 + l15;
            const float bv = bias[col];
#pragma unroll
            for (int m = 0; m < 4; ++m)
#pragma unroll
                for (int r = 0; r < 4; ++r) {
                    const int row = rowbase + m * 16 + l4 * 4 + r;
                    Cf[(size_t)row * N + col] = acc[m][n][r] + bv;
                }
        }
    } else {
#pragma unroll
        for (int n = 0; n < 4; ++n) {
            const int col = colbase + n * 16 + l15;
            const int which = col >> 10, cc = col & 1023;
            const int hh = cc >> 6, dd = cc & 63;
            const float bv = bias[col];
            const float sc = (which == 0) ? QSC : 1.0f;
#pragma unroll
            for (int m = 0; m < 4; ++m) {
                float v0 = (acc[m][n][0] + bv) * sc, v1 = (acc[m][n][1] + bv) * sc;
                float v2 = (acc[m][n][2] + bv) * sc, v3 = (acc[m][n][3] + bv) * sc;
                uint32_t pk01 = cvt_pk_bf16(v0, v1), pk23 = cvt_pk_bf16(v2, v3);
                ushort vals[4] = { (ushort)pk01, (ushort)(pk01 >> 16),
                                   (ushort)pk23, (ushort)(pk23 >> 16) };
#pragma unroll
                for (int r = 0; r < 4; ++r) {
                    const int row = rowbase + m * 16 + l4 * 4 + r;
                    const int bb = row >> 11, tt = row & 2047;
                    if (which == 0)
                        Q[(((size_t)(bb * NHEAD + hh)) * TSEQ + tt) * HDIM + dd] = vals[r];
                    else if (which == 1)
                        Kq[(((size_t)(bb * NHEAD + hh)) * TSEQ + tt) * HDIM + dd] = vals[r];
                    else
                        V[(((size_t)(bb * NHEAD + hh)) * HDIM + dd) * TSEQ + tt] = vals[r];
                }
            }
        }
    }
}

// ---------------------------------------------------------------------------
// Kernel 2: causal flash attention partials, bf16 MFMA, exact threefry drop.
// Grid x: 32 = {pair 0..15} x {half 0..1}; per pass qt = pair / 31-pair.
// Partial flash pass over half the kv range -> A (unnormalized, bf16) + m,l.
// Softmax in exp2 domain (Q pre-scaled by QSC). All exp2 = v_exp_f32,
// all bf16 packs = v_cvt_pk_bf16_f32, exact defer-rescale when max static.
// ---------------------------------------------------------------------------
__global__ __launch_bounds__(256) void attn_fwd_mfma(
    const ushort* __restrict__ Qb, const ushort* __restrict__ Kb,
    const ushort* __restrict__ VbT,
    ushort* __restrict__ Ap, float* __restrict__ mp, float* __restrict__ lp)
{
    __shared__ ushort Ks[2][64 * 64];
    __shared__ ushort Vt[2][64 * 64];
    __shared__ ushort Ps[64 * 64];
    const int tid = threadIdx.x;
    const int lane = tid & 63;
    const int wid = tid >> 6;
    const int l15 = lane & 15, l4 = lane >> 4;
    const int pair = blockIdx.x >> 1, half = blockIdx.x & 1;
    const int h = blockIdx.y, b = blockIdx.z;
    const int hb = b * NHEAD + h;
    const size_t headoff = (size_t)hb * TSEQ * HDIM;
    const ushort* Qg = Qb + headoff;
    const ushort* Kg = Kb + headoff;
    const ushort* Vg = VbT + headoff;   // [D][T] rows

    auto stage = [&](int p, int kt) {
        const ushort* Kt = Kg + (size_t)(kt * 64) * HDIM;
        const ushort* Vt0 = Vg + kt * 64;
#pragma unroll
        for (int c = 0; c < 2; ++c) {
            const int rbase = wid * 16 + c * 8;     // wave-uniform
            const int row = rbase + (lane >> 3);
            const ushort* srcK = Kt + row * 64 + (((lane & 7) * 8) ^ ((row & 7) << 3));
            async_copy16(&Ks[p][rbase * 64], srcK);
            const ushort* srcV = Vt0 + (size_t)row * TSEQ + (((lane & 7) * 8) ^ ((row & 7) << 3));
            async_copy16(&Vt[p][rbase * 64], srcV);
        }
    };

    const int swq = (l15 & 7) << 3;          // Ps swizzle (row = own q = l15)
    const int prow = wid * 16 + l15;

    for (int pass = 0; pass < 2; ++pass) {
        const int qt = pass ? (TSEQ / 64 - 1) - pair : pair;
        const int ntk = qt + 1;
        const int kb = half ? (ntk + 1) >> 1 : 0;
        const int ke = half ? ntk : (ntk + 1) >> 1;
        const int pidx = (hb * 32 + qt) * 2 + half;
        const int tilerow = wid * 16 + l15;
        ushort* arow = Ap + (size_t)pidx * 4096 + tilerow * 64;

        if (kb >= ke) {   // empty half (qt=0, half=1): neutral partial
#pragma unroll
            for (int dt = 0; dt < 4; ++dt) {
                ushort4 z; z.x = z.y = z.z = z.w = 0;
                *(ushort4*)&arow[dt * 16 + l4 * 4] = z;
            }
            if (l4 == 0) { mp[pidx * 64 + tilerow] = -INFINITY; lp[pidx * 64 + tilerow] = 0.f; }
            continue;
        }

        const int qglob = qt * 64 + tilerow;   // this thread's q row
        // Q fragments (B-operand: col=q=l15, k=d); Q is pre-scaled by QSC
        bf16x8 qf0, qf1;
        {
            const ushort* qrow = Qg + (size_t)qglob * HDIM;
            qf0 = *(const bf16x8*)(qrow + l4 * 8);
            qf1 = *(const bf16x8*)(qrow + 32 + l4 * 8);
        }

        f32x4 oacc[4];
#pragma unroll
        for (int i = 0; i < 4; ++i) oacc[i] = (f32x4){0.f, 0.f, 0.f, 0.f};
        float mi = -INFINITY, li = 0.f;
        const uint32_t rowbase = ((uint32_t)hb * TSEQ + (uint32_t)qglob) * TSEQ;

        stage(0, kb);
        __syncthreads();

        for (int kt = kb; kt < ke; ++kt) {
            const int p = (kt - kb) & 1;
            if (kt + 1 < ke) stage(p ^ 1, kt + 1);

            // ---- S^T = mfma(K, Q): lane holds q-row qglob, k = ct*16+l4*4+r
            f32x4 s4[4];
#pragma unroll
            for (int ct = 0; ct < 4; ++ct) {
                const int krow = ct * 16 + l15;
                const int sw = (krow & 7) << 3;
                bf16x8 kf0 = *(const bf16x8*)&Ks[p][krow * 64 + ((l4 * 8) ^ sw)];
                bf16x8 kf1 = *(const bf16x8*)&Ks[p][krow * 64 + ((l4 * 8 + 32) ^ sw)];
                f32x4 a = {0.f, 0.f, 0.f, 0.f};
                a = __builtin_amdgcn_mfma_f32_16x16x32_bf16(kf0, qf0, a, 0, 0, 0);
                a = __builtin_amdgcn_mfma_f32_16x16x32_bf16(kf1, qf1, a, 0, 0, 0);
                s4[ct] = a;
            }

            // ---- per-thread row softmax, exp2 domain
            const int kb0 = kt * 64;
            float ev[4][4];
            if (kt == qt) {   // diagonal tile: causal mask
#pragma unroll
                for (int ct = 0; ct < 4; ++ct)
#pragma unroll
                    for (int r = 0; r < 4; ++r) {
                        const int kglob = kb0 + ct * 16 + l4 * 4 + r;
                        ev[ct][r] = (kglob <= qglob) ? s4[ct][r] : -INFINITY;
                    }
            } else {          // full tile: no mask
#pragma unroll
                for (int ct = 0; ct < 4; ++ct)
#pragma unroll
                    for (int r = 0; r < 4; ++r) ev[ct][r] = s4[ct][r];
            }
            // max tree (max3-fusable triples)
            float mx;
            {
                float t0 = fmaxf(fmaxf(ev[0][0], ev[0][1]), ev[0][2]);
                float t1 = fmaxf(fmaxf(ev[0][3], ev[1][0]), ev[1][1]);
                float t2 = fmaxf(fmaxf(ev[1][2], ev[1][3]), ev[2][0]);
                float t3 = fmaxf(fmaxf(ev[2][1], ev[2][2]), ev[2][3]);
                float t4 = fmaxf(fmaxf(ev[3][0], ev[3][1]), ev[3][2]);
                float t5 = fmaxf(fmaxf(t0, t1), ev[3][3]);
                float t6 = fmaxf(fmaxf(t2, t3), t4);
                mx = fmaxf(t5, t6);
            }
            mx = fmaxf(mx, __shfl_xor(mx, 16));
            mx = fmaxf(mx, __shfl_xor(mx, 32));

            if (__any(mx > mi)) {               // max grew somewhere: rescale
                const float mnew = fmaxf(mi, mx);
                const float alpha = fast_exp2(mi - mnew);  // ==1 where mx<=mi
                mi = mnew;
                li *= alpha;
#pragma unroll
                for (int dt = 0; dt < 4; ++dt) {
                    oacc[dt][0] *= alpha; oacc[dt][1] *= alpha;
                    oacc[dt][2] *= alpha; oacc[dt][3] *= alpha;
                }
            }
            float rs = 0.f;
#pragma unroll
            for (int ct = 0; ct < 4; ++ct)
#pragma unroll
                for (int r = 0; r < 4; ++r) {
                    ev[ct][r] = fast_exp2(ev[ct][r] - mi);
                    rs += ev[ct][r];
                }
            rs += __shfl_xor(rs, 16);
            rs += __shfl_xor(rs, 32);
            li += rs;

            // ---- exact threefry dropout + P -> Ps (bf16 pairs, b64 writes)
            const uint32_t idx0 = rowbase + (uint32_t)kb0;
#pragma unroll
            for (int ct = 0; ct < 4; ++ct) {
                const uint32_t kk = idx0 + (uint32_t)(ct * 16 + l4 * 4);
                const float p0 = tf_keep(kk + 0u) ? ev[ct][0] : 0.f;
                const float p1 = tf_keep(kk + 1u) ? ev[ct][1] : 0.f;
                const float p2 = tf_keep(kk + 2u) ? ev[ct][2] : 0.f;
                const float p3 = tf_keep(kk + 3u) ? ev[ct][3] : 0.f;
                uint2 pk;
                pk.x = cvt_pk_bf16(p0, p1);
                pk.y = cvt_pk_bf16(p2, p3);
                *(uint2*)&Ps[prow * 64 + ((ct * 16 + l4 * 4) ^ swq)] = pk;
            }

            // ---- A^T += mfma(V^T, P): A-op=V^T[d][k], B-op=P[q][k]
            bf16x8 pf0 = *(const bf16x8*)&Ps[prow * 64 + ((l4 * 8) ^ swq)];
            bf16x8 pf1 = *(const bf16x8*)&Ps[prow * 64 + ((l4 * 8 + 32) ^ swq)];
#pragma unroll
            for (int dt = 0; dt < 4; ++dt) {
                const int drow = dt * 16 + l15;
                const int swv = (drow & 7) << 3;
                bf16x8 vf0 = *(const bf16x8*)&Vt[p][drow * 64 + ((l4 * 8) ^ swv)];
                bf16x8 vf1 = *(const bf16x8*)&Vt[p][drow * 64 + ((l4 * 8 + 32) ^ swv)];
                oacc[dt] = __builtin_amdgcn_mfma_f32_16x16x32_bf16(vf0, pf0, oacc[dt], 0, 0, 0);
                oacc[dt] = __builtin_amdgcn_mfma_f32_16x16x32_bf16(vf1, pf1, oacc[dt], 0, 0, 0);
            }
            __syncthreads();   // drains glds for kt+1; guards buffer reuse
        }

        // ---- partial epilogue: A (bf16, unnormalized), m, l
#pragma unroll
        for (int dt = 0; dt < 4; ++dt) {
            uint2 o;
            o.x = cvt_pk_bf16(oacc[dt][0], oacc[dt][1]);
            o.y = cvt_pk_bf16(oacc[dt][2], oacc[dt][3]);
            *(uint2*)&arow[dt * 16 + l4 * 4] = o;
        }
        if (l4 == 0) { mp[pidx * 64 + tilerow] = mi; lp[pidx * 64 + tilerow] = li; }
    }
}

// ---------------------------------------------------------------------------
// Kernel 2b: merge the two kv-half partials -> AO bf16 [B,T,C]
// ---------------------------------------------------------------------------
__global__ __launch_bounds__(256) void attn_merge(
    const ushort* __restrict__ Ap, const float* __restrict__ mp,
    const float* __restrict__ lp, ushort* __restrict__ AO)
{
    const int gidx = blockIdx.x * 16 + (threadIdx.x >> 4);   // 0..65535
    const int hb = gidx >> 11;          // b*16+h
    const int q  = gidx & 2047;
    const int qt = q >> 6, row = q & 63;
    const int sub = (threadIdx.x & 15) * 4;
    const int pidx0 = (hb * 32 + qt) * 2;
    const int pr = pidx0 * 64 + row;
    const float m0 = mp[pr], m1 = mp[pr + 64];
    const float l0 = lp[pr], l1 = lp[pr + 64];
    const float m  = fmaxf(m0, m1);
    const float w0 = fast_exp2(m0 - m), w1 = fast_exp2(m1 - m);
    const float inv = 1.0f / ((l0 * w0 + l1 * w1) * 0.9f);
    const float s0 = w0 * inv, s1 = w1 * inv;
    ushort4 a0 = *(const ushort4*)&Ap[(size_t)pidx0 * 4096 + row * 64 + sub];
    ushort4 a1 = *(const ushort4*)&Ap[(size_t)(pidx0 + 1) * 4096 + row * 64 + sub];
    const int b = hb >> 4, h = hb & 15;
    ushort* orow = AO + ((size_t)(b * TSEQ + q)) * CDIM + h * HDIM + sub;
    uint2 o;
    o.x = cvt_pk_bf16(bf2f(a0.x) * s0 + bf2f(a1.x) * s1,
                      bf2f(a0.y) * s0 + bf2f(a1.y) * s1);
    o.y = cvt_pk_bf16(bf2f(a0.z) * s0 + bf2f(a1.z) * s1,
                      bf2f(a0.w) * s0 + bf2f(a1.w) * s1);
    *(uint2*)orow = o;
}

// ---------------------------------------------------------------------------
extern "C" void kernel_launch(void* const* d_in, const int* in_sizes, int n_in,
                              void* d_out, int out_size, void* d_ws, size_t ws_size,
                              hipStream_t stream)
{
    const float* x      = (const float*)d_in[0];
    const float* w_attn = (const float*)d_in[1];
    const float* b_attn = (const float*)d_in[2];
    const float* w_proj = (const float*)d_in[3];
    const float* b_proj = (const float*)d_in[4];
    float* out = (float*)d_out;

    const size_t NH = (size_t)NBATCH * NHEAD * TSEQ * HDIM;   // 4,194,304
    ushort* Qb  = (ushort*)d_ws;
    ushort* Kb  = Qb + NH;
    ushort* VbT = Kb + NH;                  // bf16 [B,H,D,T]
    ushort* AO  = VbT + NH;                 // bf16 [B,T,C]
    ushort* xb  = AO + NH;                  // bf16 [4096][1024]
    ushort* wTa = xb + NH;                  // bf16 [3072][1024]
    ushort* wTp = wTa + (size_t)3072 * 1024;// bf16 [1024][1024]
    float*  mp  = (float*)(wTp + (size_t)1024 * 1024);  // [2048][64]
    float*  lp  = mp + (size_t)2048 * 64;               // [2048][64]

    // A partials (bf16, 2048 x 64 x 64 = 16.8MB) live in d_out until proj.
    ushort* Aparts = (ushort*)d_out;

    cvt_bf16<<<2048, 256, 0, stream>>>(x, xb, 4096 * 1024);
    transpose_cvt<<<dim3(96, 32), 256, 0, stream>>>(w_attn, wTa, 1024, 3072);
    transpose_cvt<<<dim3(32, 32), 256, 0, stream>>>(w_proj, wTp, 1024, 1024);

    gemm_bf16<1><<<dim3(24, 32), 256, 0, stream>>>(
        xb, wTa, b_attn, Qb, Kb, VbT, nullptr, 4096, 3072, 1024);

    attn_fwd_mfma<<<dim3(32, NHEAD, NBATCH), 256, 0, stream>>>(
        Qb, Kb, VbT, Aparts, mp, lp);

    attn_merge<<<4096, 256, 0, stream>>>(Aparts, mp, lp, AO);

    gemm_bf16<0><<<dim3(8, 32), 256, 0, stream>>>(
        AO, wTp, b_proj, nullptr, nullptr, nullptr, out, 4096, 1024, 1024);
}